// Round 4
// baseline (428.912 us; speedup 1.0000x reference)
//
#include <hip/hip_runtime.h>
#include <hip/hip_bf16.h>
#include <math.h>
#include <type_traits>

// Round 4:
//  - gemm_v_res epilogue rebuilt: acc -> LDS (bf16, 4x 32-row chunks, padded rows)
//    -> vectorized short8 e1/e2 loads + res stores (was 128 scalar 2B loads/lane).
//  - XCD-aware bijective block swizzle on all 128x128-tile GEMMs (T1).
//  - chain_k: atomics removed -> per-block partial colsums + cs1_reduce_k
//    (coalesced reduce, writes reciprocals directly).

typedef __attribute__((ext_vector_type(8))) short short8;
typedef __attribute__((ext_vector_type(4))) float f32x4;

#define GLOAD_LDS16(gptr, lptr)                                                 \
    __builtin_amdgcn_global_load_lds(                                           \
        (const __attribute__((address_space(1))) void*)(gptr),                  \
        (__attribute__((address_space(3))) void*)(lptr), 16, 0, 0)

static __device__ __forceinline__ unsigned short f2bf_bits(float v) {
    __hip_bfloat16 h = __float2bfloat16(v);
    return __builtin_bit_cast(unsigned short, h);
}
static __device__ __forceinline__ float bf_bits2f(unsigned short u) {
    return __bfloat162float(__builtin_bit_cast(__hip_bfloat16, u));
}
// swizzled chunk index for 16B chunk (r, c16) in a [R][128-elem] bf16 tile
static __device__ __forceinline__ int swz16(int r, int c16) {
    return (r << 4) + (c16 ^ (r & 7));
}
// swizzled ushort index for element (r, c) in [R][128] bf16 tile
static __device__ __forceinline__ int swz_elem(int r, int c) {
    return (r << 7) + ((((c << 1) ^ ((r & 7) << 4))) >> 1);
}

__global__ void zero_k(float* __restrict__ p, int n) {
    int i = blockIdx.x * 256 + threadIdx.x;
    if (i < n) p[i] = 0.f;
}

__global__ void invde_k(float* __restrict__ invde) {
    int i = blockIdx.x * 256 + threadIdx.x;
    if (i < 512) invde[i] = exp2f(-9.96578428466209f * (float)i * (1.f / 512.f));
}

__global__ void rcs_k(float* __restrict__ cs, int n) {
    int i = blockIdx.x * 256 + threadIdx.x;
    if (i < n) cs[i] = 1.f / cs[i];
}

__global__ void conv_k(const float* __restrict__ in, __hip_bfloat16* __restrict__ out, int n) {
    int i = blockIdx.x * 256 + threadIdx.x;
    if (i < n) out[i] = __float2bfloat16(in[i]);
}

// transpose + convert: A[K][N] fp32 (optionally minus Bsub) -> Ot[N][K] bf16
__global__ __launch_bounds__(256) void conv_t_k(
    const float* __restrict__ A, const float* __restrict__ Bsub,
    __hip_bfloat16* __restrict__ Ot, int K, int N)
{
    __shared__ float t[32][33];
    const int n0 = blockIdx.x * 32, k0 = blockIdx.y * 32;
    const int tx = threadIdx.x, ty = threadIdx.y;  // (32,8)
    #pragma unroll
    for (int j = 0; j < 4; ++j) {
        int k = k0 + ty + j * 8;
        float v = A[(long)k * N + n0 + tx];
        if (Bsub) v -= Bsub[(long)k * N + n0 + tx];
        t[ty + j * 8][tx] = v;
    }
    __syncthreads();
    #pragma unroll
    for (int j = 0; j < 4; ++j) {
        int n = n0 + ty + j * 8;
        Ot[(long)n * K + k0 + tx] = __float2bfloat16(t[tx][ty + j * 8]);
    }
}

// XCD-bijective swizzle for linear bid with nwg % 8 == 0:
// XCD x gets contiguous work chunk [x*(nwg/8), (x+1)*(nwg/8)).
static __device__ __forceinline__ int xcd_swz(int bid, int nwg) {
    return (bid & 7) * (nwg >> 3) + (bid >> 3);
}

// ---------------- generic 128x128 MFMA GEMM ----------------
// C[M,N] = op(A[M,K] @ B + bias), Bt = B^T [N][K] bf16. OP: 0 none, 1 relu, 2 exp(x*scale)
// grid: dim3(8, M/128). N must be 1024 (bn = swz&7 << 7).
template <int OP, typename OutT>
__global__ __launch_bounds__(256) void gemm_bf16(
    const __hip_bfloat16* __restrict__ A, const __hip_bfloat16* __restrict__ Bt,
    const float* __restrict__ bias, OutT* __restrict__ Co,
    int M, int Nn, int K, float scale)
{
    __shared__ __hip_bfloat16 As[128 * 32];
    __shared__ __hip_bfloat16 Bs[128 * 32];
    const int tid = threadIdx.x;
    const int wid = tid >> 6;
    const int lane = tid & 63;
    const int nwg = gridDim.x * gridDim.y;
    const int swz = xcd_swz(blockIdx.y * gridDim.x + blockIdx.x, nwg);
    const int bm = (swz >> 3) << 7, bn = (swz & 7) << 7;
    const int wm = (wid >> 1) << 6, wn = (wid & 1) << 6;

    f32x4 acc[4][4] = {};

    const int idx0 = tid, idx1 = tid + 256;
    const int r0 = idx0 >> 2, c0 = (idx0 & 3) << 3;
    const int r1 = idx1 >> 2, c1 = (idx1 & 3) << 3;
    __hip_bfloat16* lA0 = As + (size_t)(0 * 256 + (wid << 6)) * 8;
    __hip_bfloat16* lA1 = As + (size_t)(1 * 256 + (wid << 6)) * 8;
    __hip_bfloat16* lB0 = Bs + (size_t)(0 * 256 + (wid << 6)) * 8;
    __hip_bfloat16* lB1 = Bs + (size_t)(1 * 256 + (wid << 6)) * 8;

    const int arow = wm + (lane & 15);
    const int brow = wn + (lane & 15);
    const int kg = lane >> 4;

    for (int k0 = 0; k0 < K; k0 += 32) {
        GLOAD_LDS16(A + (long)(bm + r0) * K + k0 + c0, lA0);
        GLOAD_LDS16(A + (long)(bm + r1) * K + k0 + c1, lA1);
        GLOAD_LDS16(Bt + (long)(bn + r0) * K + k0 + c0, lB0);
        GLOAD_LDS16(Bt + (long)(bn + r1) * K + k0 + c1, lB1);
        __syncthreads();

        short8 af[4], bf_[4];
        #pragma unroll
        for (int m = 0; m < 4; ++m)
            af[m] = ((const short8*)As)[(arow + m * 16) * 4 + kg];
        #pragma unroll
        for (int n = 0; n < 4; ++n)
            bf_[n] = ((const short8*)Bs)[(brow + n * 16) * 4 + kg];
        #pragma unroll
        for (int m = 0; m < 4; ++m)
            #pragma unroll
            for (int n = 0; n < 4; ++n)
                acc[m][n] = __builtin_amdgcn_mfma_f32_16x16x32_bf16(
                    af[m], bf_[n], acc[m][n], 0, 0, 0);
        __syncthreads();
    }

    const int rq = (lane >> 4) << 2;
    #pragma unroll
    for (int n = 0; n < 4; ++n) {
        const int col = bn + wn + n * 16 + (lane & 15);
        const float bv = bias ? bias[col] : 0.f;
        #pragma unroll
        for (int m = 0; m < 4; ++m) {
            #pragma unroll
            for (int j = 0; j < 4; ++j) {
                const int row = bm + wm + m * 16 + rq + j;
                float cv = acc[m][n][j] + bv;
                if (OP == 1) cv = fmaxf(cv, 0.f);
                if (OP == 2) cv = __expf(cv * scale);
                if constexpr (std::is_same<OutT, float>::value)
                    Co[(long)row * Nn + col] = cv;
                else
                    Co[(long)row * Nn + col] = __float2bfloat16(cv);
            }
        }
    }
}

// ---------------- fused group-MLP chain ----------------
// x flat [131072][128] bf16; per block: 128 rows. In-LDS chain:
// d1 = x@w1T ; t = relu(d1@w2T + b2) ; e = exp((t@w3T + b3)/sqrt(128))
// e1 written bf16; per-block column partials -> pcs1[bid][1024].
__global__ __launch_bounds__(256) void chain_k(
    const __hip_bfloat16* __restrict__ xb,
    const __hip_bfloat16* __restrict__ w1T,
    const __hip_bfloat16* __restrict__ w2T,
    const __hip_bfloat16* __restrict__ w3T,
    const float* __restrict__ b2, const float* __restrict__ b3,
    __hip_bfloat16* __restrict__ e1, float* __restrict__ pcs1)
{
    __shared__ unsigned short act[128 * 128];  // 32 KB, swizzled
    __shared__ unsigned short Wb[128 * 128];   // 32 KB, swizzled (streamed W1->W2->W3)
    const int tid = threadIdx.x, wid = tid >> 6, lane = tid & 63;
    const int wm = (wid >> 1) << 6, wn = (wid & 1) << 6;
    const long tile = (long)blockIdx.x * (128 * 128);

    #pragma unroll
    for (int i = 0; i < 8; ++i) {
        int L = i * 256 + wid * 64 + lane;
        int r = L >> 4, c16o = (L & 15) ^ (r & 7);
        GLOAD_LDS16(xb + tile + r * 128 + c16o * 8,
                    (char*)act + (i * 256 + wid * 64) * 16);
        GLOAD_LDS16(w1T + r * 128 + c16o * 8,
                    (char*)Wb + (i * 256 + wid * 64) * 16);
    }
    __syncthreads();

    f32x4 acc[4][4];
    const int rq = (lane >> 4) << 2;

#define CHAIN_ZERO()                                                            \
    _Pragma("unroll") for (int m = 0; m < 4; ++m)                               \
        _Pragma("unroll") for (int n = 0; n < 4; ++n)                           \
            acc[m][n] = (f32x4){0.f, 0.f, 0.f, 0.f};

#define CHAIN_MM()                                                              \
    _Pragma("unroll") for (int ks = 0; ks < 4; ++ks) {                          \
        short8 af[4], bfv[4];                                                   \
        const int kc = ks * 4 + (lane >> 4);                                    \
        _Pragma("unroll") for (int m = 0; m < 4; ++m) {                         \
            int r = wm + m * 16 + (lane & 15);                                  \
            af[m] = *(const short8*)((const char*)act + swz16(r, kc) * 16);     \
        }                                                                       \
        _Pragma("unroll") for (int n = 0; n < 4; ++n) {                         \
            int r = wn + n * 16 + (lane & 15);                                  \
            bfv[n] = *(const short8*)((const char*)Wb + swz16(r, kc) * 16);     \
        }                                                                       \
        _Pragma("unroll") for (int m = 0; m < 4; ++m)                           \
            _Pragma("unroll") for (int n = 0; n < 4; ++n)                       \
                acc[m][n] = __builtin_amdgcn_mfma_f32_16x16x32_bf16(            \
                    af[m], bfv[n], acc[m][n], 0, 0, 0);                         \
    }

#define STAGE_W(wptr)                                                           \
    _Pragma("unroll") for (int i = 0; i < 8; ++i) {                             \
        int L = i * 256 + wid * 64 + lane;                                      \
        int r = L >> 4, c16o = (L & 15) ^ (r & 7);                              \
        GLOAD_LDS16((wptr) + r * 128 + c16o * 8,                                \
                    (char*)Wb + (i * 256 + wid * 64) * 16);                     \
    }

    // ---- stage 1: d1 = x @ w1T ----
    CHAIN_ZERO(); CHAIN_MM();
    __syncthreads();
    STAGE_W(w2T);
    #pragma unroll
    for (int m = 0; m < 4; ++m)
        #pragma unroll
        for (int n = 0; n < 4; ++n)
            #pragma unroll
            for (int j = 0; j < 4; ++j) {
                int row = wm + m * 16 + rq + j, col = wn + n * 16 + (lane & 15);
                act[swz_elem(row, col)] = f2bf_bits(acc[m][n][j]);
            }
    __syncthreads();

    // ---- stage 2: t = relu(d1 @ w2T + b2) ----
    CHAIN_ZERO(); CHAIN_MM();
    __syncthreads();
    STAGE_W(w3T);
    {
        float bv[4];
        #pragma unroll
        for (int n = 0; n < 4; ++n) bv[n] = b2[wn + n * 16 + (lane & 15)];
        #pragma unroll
        for (int m = 0; m < 4; ++m)
            #pragma unroll
            for (int n = 0; n < 4; ++n)
                #pragma unroll
                for (int j = 0; j < 4; ++j) {
                    int row = wm + m * 16 + rq + j, col = wn + n * 16 + (lane & 15);
                    act[swz_elem(row, col)] = f2bf_bits(fmaxf(acc[m][n][j] + bv[n], 0.f));
                }
    }
    __syncthreads();

    // ---- stage 3: e = exp((t @ w3T + b3) / sqrt(128)) ----
    CHAIN_ZERO(); CHAIN_MM();
    __syncthreads();
    {
        float bv[4];
        #pragma unroll
        for (int n = 0; n < 4; ++n) bv[n] = b3[wn + n * 16 + (lane & 15)];
        #pragma unroll
        for (int m = 0; m < 4; ++m)
            #pragma unroll
            for (int n = 0; n < 4; ++n)
                #pragma unroll
                for (int j = 0; j < 4; ++j) {
                    int row = wm + m * 16 + rq + j, col = wn + n * 16 + (lane & 15);
                    float ev = __expf((acc[m][n][j] + bv[n]) * 0.08838834764831845f);
                    act[swz_elem(row, col)] = f2bf_bits(ev);
                }
    }
    __syncthreads();

    // copy act -> e1 (global, linear): unswizzle via swizzled LDS reads
    #pragma unroll
    for (int i = 0; i < 8; ++i) {
        int idx = i * 256 + tid;
        int r = idx >> 4, c16o = idx & 15;
        short8 vd = *(const short8*)((const char*)act + swz16(r, c16o) * 16);
        *(short8*)((__hip_bfloat16*)e1 + tile + r * 128 + c16o * 8) = vd;
    }
    // per-block column partials: (g,c) -> sum over 16 rows with row&7==g
    #pragma unroll
    for (int i = 0; i < 4; ++i) {
        int p = i * 256 + tid;
        int g = p >> 7, c = p & 127;
        float s = 0.f;
        #pragma unroll
        for (int t16 = 0; t16 < 16; ++t16) {
            int r = t16 * 8 + g;
            s += bf_bits2f(act[swz_elem(r, c)]);
        }
        pcs1[(long)blockIdx.x * 1024 + p] = s;
    }
#undef CHAIN_ZERO
#undef CHAIN_MM
#undef STAGE_W
}

// reduce pcs1[1024][1024] over blocks -> rcs1[col] = 1/sum. grid 16, block (64,4)
__global__ void cs1_reduce_k(const float* __restrict__ pcs1, float* __restrict__ rcs1)
{
    const int col = blockIdx.x * 64 + threadIdx.x;
    float s = 0.f;
    for (int p = threadIdx.y; p < 1024; p += 4)
        s += pcs1[(long)p * 1024 + col];
    __shared__ float red[4][64];
    red[threadIdx.y][threadIdx.x] = s;
    __syncthreads();
    if (threadIdx.y == 0)
        rcs1[col] = 1.f / (red[0][threadIdx.x] + red[1][threadIdx.x] +
                           red[2][threadIdx.x] + red[3][threadIdx.x]);
}

// ---------------- v-GEMM with fused vectorized res epilogue ----------------
// res[n][h] = (e1[n][h]*rcs1[h] + e2[n&2047][h]*rcs2[h]) * (v[n][h] + pe(n,h))
__global__ __launch_bounds__(256) void gemm_v_res(
    const __hip_bfloat16* __restrict__ A, const __hip_bfloat16* __restrict__ Bt,
    const __hip_bfloat16* __restrict__ e1, const __hip_bfloat16* __restrict__ e2,
    const float* __restrict__ rcs1, const float* __restrict__ rcs2,
    const float* __restrict__ invde, const float* __restrict__ feats,
    const float* __restrict__ lpe, __hip_bfloat16* __restrict__ res, int K)
{
    __shared__ __align__(16) char smem[16384];
    __hip_bfloat16* As = (__hip_bfloat16*)smem;            // 8 KB
    __hip_bfloat16* Bs = (__hip_bfloat16*)(smem + 8192);   // 8 KB
    unsigned short* st = (unsigned short*)smem;            // [32][136] bf16, 8704 B (epilogue)

    const int tid = threadIdx.x;
    const int wid = tid >> 6;
    const int lane = tid & 63;
    const int swz = xcd_swz(blockIdx.y * gridDim.x + blockIdx.x, gridDim.x * gridDim.y);
    const int bm = (swz >> 3) << 7, bn = (swz & 7) << 7;
    const int wm = (wid >> 1) << 6, wn = (wid & 1) << 6;

    f32x4 acc[4][4] = {};

    const int idx0 = tid, idx1 = tid + 256;
    const int r0 = idx0 >> 2, c0s = (idx0 & 3) << 3;
    const int r1 = idx1 >> 2, c1s = (idx1 & 3) << 3;
    __hip_bfloat16* lA0 = As + (size_t)(0 * 256 + (wid << 6)) * 8;
    __hip_bfloat16* lA1 = As + (size_t)(1 * 256 + (wid << 6)) * 8;
    __hip_bfloat16* lB0 = Bs + (size_t)(0 * 256 + (wid << 6)) * 8;
    __hip_bfloat16* lB1 = Bs + (size_t)(1 * 256 + (wid << 6)) * 8;

    const int arow = wm + (lane & 15);
    const int brow = wn + (lane & 15);
    const int kg = lane >> 4;

    for (int k0 = 0; k0 < K; k0 += 32) {
        GLOAD_LDS16(A + (long)(bm + r0) * K + k0 + c0s, lA0);
        GLOAD_LDS16(A + (long)(bm + r1) * K + k0 + c1s, lA1);
        GLOAD_LDS16(Bt + (long)(bn + r0) * K + k0 + c0s, lB0);
        GLOAD_LDS16(Bt + (long)(bn + r1) * K + k0 + c1s, lB1);
        __syncthreads();

        short8 af[4], bf_[4];
        #pragma unroll
        for (int m = 0; m < 4; ++m)
            af[m] = ((const short8*)As)[(arow + m * 16) * 4 + kg];
        #pragma unroll
        for (int n = 0; n < 4; ++n)
            bf_[n] = ((const short8*)Bs)[(brow + n * 16) * 4 + kg];
        #pragma unroll
        for (int m = 0; m < 4; ++m)
            #pragma unroll
            for (int n = 0; n < 4; ++n)
                acc[m][n] = __builtin_amdgcn_mfma_f32_16x16x32_bf16(
                    af[m], bf_[n], acc[m][n], 0, 0, 0);
        __syncthreads();
    }

    const float lp = lpe[0];
    const int rq = (lane >> 4) << 2;
    const int l15 = lane & 15;

    // 4 chunks of 32 rows: acc -> LDS (bf16) -> vectorized global epilogue
    #pragma unroll
    for (int t = 0; t < 4; ++t) {
        __syncthreads();  // previous chunk's reads done
        if ((wid >> 1) == (t >> 1)) {
            const int m0 = (t & 1) << 1;
            #pragma unroll
            for (int mm = 0; mm < 2; ++mm)
                #pragma unroll
                for (int n = 0; n < 4; ++n)
                    #pragma unroll
                    for (int j = 0; j < 4; ++j)
                        st[(mm * 16 + rq + j) * 136 + wn + n * 16 + l15] =
                            f2bf_bits(acc[m0 + mm][n][j]);
        }
        __syncthreads();

        const int r = tid >> 3;             // 0..31
        const int cc = (tid & 7) << 4;      // 0..112 step 16
        const int grow = bm + t * 32 + r;
        const float angs = 100.f * feats[(long)grow * 64];
        const long goff = (long)grow * 1024 + bn + cc;
        const long goff2 = (long)(grow & 2047) * 1024 + bn + cc;
        short8 ev1[2], ev2[2], sv[2];
        ev1[0] = *(const short8*)((const unsigned short*)e1 + goff);
        ev1[1] = *(const short8*)((const unsigned short*)e1 + goff + 8);
        ev2[0] = *(const short8*)((const unsigned short*)e2 + goff2);
        ev2[1] = *(const short8*)((const unsigned short*)e2 + goff2 + 8);
        sv[0] = *(const short8*)&st[r * 136 + cc];
        sv[1] = *(const short8*)&st[r * 136 + cc + 8];
        unsigned short ov[16];
        #pragma unroll
        for (int q = 0; q < 16; ++q) {
            const int h = bn + cc + q;
            const float ang = angs * invde[h & 511];
            const float tr = (h < 512) ? __sinf(ang) : __cosf(ang);
            const float a = bf_bits2f((unsigned short)ev1[q >> 3][q & 7]) * rcs1[h] +
                            bf_bits2f((unsigned short)ev2[q >> 3][q & 7]) * rcs2[h];
            const float vv = bf_bits2f((unsigned short)sv[q >> 3][q & 7]);
            ov[q] = f2bf_bits(a * (vv + (tr + lp) * lp));
        }
        *(short8*)((unsigned short*)res + goff) = *(short8*)&ov[0];
        *(short8*)((unsigned short*)res + goff + 8) = *(short8*)&ov[8];
    }
}

// ---------------- out = res @ fc2_w + fc2_b + features ----------------
__global__ __launch_bounds__(256) void out_gemm_k(
    const __hip_bfloat16* __restrict__ res, const __hip_bfloat16* __restrict__ fc2T,
    const float* __restrict__ fc2_b, const float* __restrict__ feats,
    float* __restrict__ out)
{
    __shared__ unsigned short As[64 * 64];
    __shared__ unsigned short Bs[64 * 64];
    const int tid = threadIdx.x, wid = tid >> 6, lane = tid & 63;
    const int bm = blockIdx.x << 6;
    f32x4 acc[4] = {};

    for (int k0 = 0; k0 < 1024; k0 += 64) {
        #pragma unroll
        for (int i = 0; i < 2; ++i) {
            int L = i * 256 + wid * 64 + lane;
            int r = L >> 3, c16o = (L & 7) ^ (r & 7);
            GLOAD_LDS16(res + (long)(bm + r) * 1024 + k0 + c16o * 8,
                        (char*)As + (i * 256 + wid * 64) * 16);
            GLOAD_LDS16(fc2T + (long)r * 1024 + k0 + c16o * 8,
                        (char*)Bs + (i * 256 + wid * 64) * 16);
        }
        __syncthreads();
        #pragma unroll
        for (int ks = 0; ks < 2; ++ks) {
            const int kc = ks * 4 + (lane >> 4);
            const int ar = wid * 16 + (lane & 15);
            short8 af = *(const short8*)((const char*)As + ((ar << 3) + (kc ^ (ar & 7))) * 16);
            #pragma unroll
            for (int n = 0; n < 4; ++n) {
                const int br = n * 16 + (lane & 15);
                short8 bfv = *(const short8*)((const char*)Bs + ((br << 3) + (kc ^ (br & 7))) * 16);
                acc[n] = __builtin_amdgcn_mfma_f32_16x16x32_bf16(af, bfv, acc[n], 0, 0, 0);
            }
        }
        __syncthreads();
    }
    const int rq = (lane >> 4) << 2;
    #pragma unroll
    for (int n = 0; n < 4; ++n) {
        const int col = n * 16 + (lane & 15);
        const float bv = fc2_b[col];
        #pragma unroll
        for (int j = 0; j < 4; ++j) {
            const int row = bm + wid * 16 + rq + j;
            out[(long)row * 64 + col] = acc[n][j] + bv + feats[(long)row * 64 + col];
        }
    }
}

// column sums of bf16 e [M][1024] -> colsum (atomics; small, deterministic enough)
__global__ void colsum_bf_k(const __hip_bfloat16* __restrict__ e, float* __restrict__ colsum,
                            int M, int Nn)
{
    const int c = blockIdx.x * 64 + threadIdx.x;
    const int chunk = M / gridDim.y;
    const int r0 = blockIdx.y * chunk;
    float s = 0.f;
    for (int r = r0 + threadIdx.y; r < r0 + chunk; r += 4)
        s += __bfloat162float(e[(long)r * Nn + c]);
    __shared__ float red[4][64];
    red[threadIdx.y][threadIdx.x] = s;
    __syncthreads();
    if (threadIdx.y == 0)
        atomicAdd(&colsum[c],
                  red[0][threadIdx.x] + red[1][threadIdx.x] +
                  red[2][threadIdx.x] + red[3][threadIdx.x]);
}

extern "C" void kernel_launch(void* const* d_in, const int* in_sizes, int n_in,
                              void* d_out, int out_size, void* d_ws, size_t ws_size,
                              hipStream_t stream) {
    const float* features = (const float*)d_in[0];
    const float* fc1_w = (const float*)d_in[1];
    const float* fc1_b = (const float*)d_in[2];
    const float* fc2_w = (const float*)d_in[3];
    const float* fc2_b = (const float*)d_in[4];
    const float* g1_w = (const float*)d_in[5];
    const float* g1_b = (const float*)d_in[6];
    const float* g2_w = (const float*)d_in[7];
    const float* g2_b = (const float*)d_in[8];
    const float* gg1_w = (const float*)d_in[9];
    const float* gg1_b = (const float*)d_in[10];
    const float* gg2_w = (const float*)d_in[11];
    const float* gg2_b = (const float*)d_in[12];
    const float* wq = (const float*)d_in[13];
    const float* wk = (const float*)d_in[14];
    const float* wv = (const float*)d_in[15];
    const float* wq2 = (const float*)d_in[16];
    const float* wk2 = (const float*)d_in[17];
    const float* lpe = (const float*)d_in[18];
    float* out = (float*)d_out;

    char* ws = (char*)d_ws;
    const size_t MB = 1024ull * 1024ull;
    __hip_bfloat16* xb   = (__hip_bfloat16*)ws;                 // 32 MB
    __hip_bfloat16* e1   = (__hip_bfloat16*)(ws + 32 * MB);     // 32 MB
    __hip_bfloat16* resb = (__hip_bfloat16*)(ws + 64 * MB);     // 32 MB
    __hip_bfloat16* d2b  = (__hip_bfloat16*)(ws + 96 * MB);     // 4 MB
    __hip_bfloat16* t2b  = (__hip_bfloat16*)(ws + 100 * MB);    // 4 MB
    __hip_bfloat16* e2b  = (__hip_bfloat16*)(ws + 104 * MB);    // 4 MB
    float*          pcs1 = (float*)(ws + 108 * MB);             // 4 MB (1024x1024 partials)
    char* W = ws + 116 * MB;
    __hip_bfloat16* featb = (__hip_bfloat16*)W;                 // 2 MB
    __hip_bfloat16* fc1T  = (__hip_bfloat16*)(W + 2 * MB);      // 128 KB
    __hip_bfloat16* wdT   = (__hip_bfloat16*)(W + 3 * MB);      // 2 MB
    __hip_bfloat16* wvT   = (__hip_bfloat16*)(W + 5 * MB);      // 2 MB
    __hip_bfloat16* g1T   = (__hip_bfloat16*)(W + 7 * MB);      // 2 MB
    __hip_bfloat16* g2T   = (__hip_bfloat16*)(W + 9 * MB);      // 2 MB
    __hip_bfloat16* fc2T  = (__hip_bfloat16*)(W + 11 * MB);     // 128 KB
    __hip_bfloat16* wd2T  = (__hip_bfloat16*)(W + 12 * MB);     // 32 KB
    __hip_bfloat16* gg1T  = (__hip_bfloat16*)(W + 12 * MB + 64 * 1024);
    __hip_bfloat16* gg2T  = (__hip_bfloat16*)(W + 12 * MB + 128 * 1024);
    float* rcs1  = (float*)(W + 13 * MB);                       // 4 KB
    float* cs2   = rcs1 + 1024;
    float* invde = cs2 + 1024;                                  // 512

    zero_k<<<4, 256, 0, stream>>>(cs2, 1024);
    invde_k<<<2, 256, 0, stream>>>(invde);
    conv_k<<<4096, 256, 0, stream>>>(features, featb, 16384 * 64);
    conv_t_k<<<dim3(32, 2),  dim3(32, 8), 0, stream>>>(fc1_w, nullptr, fc1T, 64, 1024);
    conv_t_k<<<dim3(32, 32), dim3(32, 8), 0, stream>>>(wq, wk, wdT, 1024, 1024);
    conv_t_k<<<dim3(32, 32), dim3(32, 8), 0, stream>>>(wv, nullptr, wvT, 1024, 1024);
    conv_t_k<<<dim3(32, 32), dim3(32, 8), 0, stream>>>(g1_w, nullptr, g1T, 1024, 1024);
    conv_t_k<<<dim3(32, 32), dim3(32, 8), 0, stream>>>(g2_w, nullptr, g2T, 1024, 1024);
    conv_t_k<<<dim3(2, 32),  dim3(32, 8), 0, stream>>>(fc2_w, nullptr, fc2T, 1024, 64);
    conv_t_k<<<dim3(4, 4),   dim3(32, 8), 0, stream>>>(wq2, wk2, wd2T, 128, 128);
    conv_t_k<<<dim3(4, 4),   dim3(32, 8), 0, stream>>>(gg1_w, nullptr, gg1T, 128, 128);
    conv_t_k<<<dim3(4, 4),   dim3(32, 8), 0, stream>>>(gg2_w, nullptr, gg2T, 128, 128);

    // x = features @ fc1_w + fc1_b
    gemm_bf16<0, __hip_bfloat16><<<dim3(8, 128), 256, 0, stream>>>(
        featb, fc1T, fc1_b, xb, 16384, 1024, 64, 0.f);

    // fused group chain -> e1 bf16 + pcs1; reduce -> rcs1
    chain_k<<<1024, 256, 0, stream>>>(xb, wd2T, gg1T, gg2T, gg1_b, gg2_b, e1, pcs1);
    cs1_reduce_k<<<16, dim3(64, 4), 0, stream>>>(pcs1, rcs1);

    // tail branch
    gemm_bf16<0, __hip_bfloat16><<<dim3(8, 16), 256, 0, stream>>>(
        xb + (size_t)14336 * 1024, wdT, nullptr, d2b, 2048, 1024, 1024, 0.f);
    gemm_bf16<1, __hip_bfloat16><<<dim3(8, 16), 256, 0, stream>>>(
        d2b, g1T, g1_b, t2b, 2048, 1024, 1024, 0.f);
    gemm_bf16<2, __hip_bfloat16><<<dim3(8, 16), 256, 0, stream>>>(
        t2b, g2T, g2_b, e2b, 2048, 1024, 1024, 0.03125f);
    colsum_bf_k<<<dim3(16, 8), dim3(64, 4), 0, stream>>>(e2b, cs2, 2048, 1024);
    rcs_k<<<4, 256, 0, stream>>>(cs2, 1024);

    // v-GEMM + fused vectorized res epilogue
    gemm_v_res<<<dim3(8, 128), 256, 0, stream>>>(
        xb, wvT, e1, e2b, rcs1, cs2, invde, features, lpe, resb, 1024);

    // out = res @ fc2_w + fc2_b + features
    out_gemm_k<<<256, 256, 0, stream>>>(resb, fc2T, fc2_b, features, out);
}

// Round 5
// 392.290 us; speedup vs baseline: 1.0934x; 1.0934x over previous
//
#include <hip/hip_runtime.h>
#include <hip/hip_bf16.h>
#include <math.h>
#include <type_traits>

// Round 5: launch-count 20 -> 9.
//  - prep_k: ONE kernel for feature conv, all 9 weight transposes (+wq-wk fusion),
//    invde LUT, and out-init (out = features + fc2_b).
//  - tail e2 GEMM fuses its column-sum (LDS partials -> pcs2, no atomics).
//  - reduce_k: one kernel -> rcs1 (from pcs1) and rcs2 (from pcs2), reciprocals.
//  - out_gemm_sk: split-K=2, 256 blocks, fp32 atomicAdd into pre-initialized out.
//  - gemm_v_res: single-chunk epilogue (128x136 LDS union), 2 barriers not 8.

typedef __attribute__((ext_vector_type(8))) short short8;
typedef __attribute__((ext_vector_type(4))) float f32x4;

#define GLOAD_LDS16(gptr, lptr)                                                 \
    __builtin_amdgcn_global_load_lds(                                           \
        (const __attribute__((address_space(1))) void*)(gptr),                  \
        (__attribute__((address_space(3))) void*)(lptr), 16, 0, 0)

static __device__ __forceinline__ unsigned short f2bf_bits(float v) {
    __hip_bfloat16 h = __float2bfloat16(v);
    return __builtin_bit_cast(unsigned short, h);
}
static __device__ __forceinline__ float bf_bits2f(unsigned short u) {
    return __bfloat162float(__builtin_bit_cast(__hip_bfloat16, u));
}
static __device__ __forceinline__ int swz16(int r, int c16) {
    return (r << 4) + (c16 ^ (r & 7));
}
static __device__ __forceinline__ int swz_elem(int r, int c) {
    return (r << 7) + ((((c << 1) ^ ((r & 7) << 4))) >> 1);
}
static __device__ __forceinline__ int xcd_swz(int bid, int nwg) {
    return (bid & 7) * (nwg >> 3) + (bid >> 3);
}

// ---------------- prep: everything small in one launch ----------------
static __device__ void conv_t_dev(const float* __restrict__ A, const float* __restrict__ Bsub,
                                  __hip_bfloat16* __restrict__ Ot, int K, int N,
                                  int bx, int by, int tid, float* t /* [32][33] */)
{
    const int n0 = bx * 32, k0 = by * 32;
    const int tx = tid & 31, ty = tid >> 5;
    #pragma unroll
    for (int j = 0; j < 4; ++j) {
        int k = k0 + ty + j * 8;
        float v = A[(long)k * N + n0 + tx];
        if (Bsub) v -= Bsub[(long)k * N + n0 + tx];
        t[(ty + j * 8) * 33 + tx] = v;
    }
    __syncthreads();
    #pragma unroll
    for (int j = 0; j < 4; ++j) {
        int n = n0 + ty + j * 8;
        Ot[(long)n * K + k0 + tx] = __float2bfloat16(t[tx * 33 + ty + j * 8]);
    }
}

typedef __attribute__((ext_vector_type(4))) float float4v;

__global__ __launch_bounds__(256) void prep_k(
    const float* __restrict__ features, const float* __restrict__ fc1_w,
    const float* __restrict__ fc2_w, const float* __restrict__ fc2_b,
    const float* __restrict__ g1_w, const float* __restrict__ g2_w,
    const float* __restrict__ wq, const float* __restrict__ wk,
    const float* __restrict__ wv, const float* __restrict__ wq2,
    const float* __restrict__ wk2, const float* __restrict__ gg1_w,
    const float* __restrict__ gg2_w,
    __hip_bfloat16* __restrict__ featb, __hip_bfloat16* __restrict__ fc1T,
    __hip_bfloat16* __restrict__ fc2T, __hip_bfloat16* __restrict__ wdT,
    __hip_bfloat16* __restrict__ wvT, __hip_bfloat16* __restrict__ g1T,
    __hip_bfloat16* __restrict__ g2T, __hip_bfloat16* __restrict__ wd2T,
    __hip_bfloat16* __restrict__ gg1T, __hip_bfloat16* __restrict__ gg2T,
    float* __restrict__ invde, float* __restrict__ out)
{
    __shared__ float t[32 * 33];
    const int bid = blockIdx.x;
    const int tid = threadIdx.x;

    if (bid == 0) {                       // invde LUT (512)
        #pragma unroll
        for (int i = 0; i < 2; ++i) {
            int idx = tid + i * 256;
            invde[idx] = exp2f(-9.96578428466209f * (float)idx * (1.f / 512.f));
        }
    } else if (bid < 257) {               // out = features + fc2_b  (1M fp32)
        const float4v* f4 = (const float4v*)features;
        float4v* o4 = (float4v*)out;
        const float4v* b4 = (const float4v*)fc2_b;
        long base = (long)(bid - 1) * 1024;
        #pragma unroll
        for (int i = 0; i < 4; ++i) {
            long idx = base + tid + i * 256;
            o4[idx] = f4[idx] + b4[idx & 15];
        }
    } else if (bid < 769) {               // features -> bf16 (1M elems, 8/thread)
        long j = (long)(bid - 257) * 256 + tid;
        const float4v* f4 = (const float4v*)features;
        float4v a = f4[j * 2], b = f4[j * 2 + 1];
        unsigned short o[8];
        #pragma unroll
        for (int q = 0; q < 4; ++q) { o[q] = f2bf_bits(a[q]); o[4 + q] = f2bf_bits(b[q]); }
        *(short8*)((unsigned short*)featb + j * 8) = *(short8*)o;
    } else if (bid < 1793) {              // wdT = (wq - wk)^T
        int tt = bid - 769;  conv_t_dev(wq, wk, wdT, 1024, 1024, tt & 31, tt >> 5, tid, t);
    } else if (bid < 2817) {              // wvT
        int tt = bid - 1793; conv_t_dev(wv, nullptr, wvT, 1024, 1024, tt & 31, tt >> 5, tid, t);
    } else if (bid < 3841) {              // g1T
        int tt = bid - 2817; conv_t_dev(g1_w, nullptr, g1T, 1024, 1024, tt & 31, tt >> 5, tid, t);
    } else if (bid < 4865) {              // g2T
        int tt = bid - 3841; conv_t_dev(g2_w, nullptr, g2T, 1024, 1024, tt & 31, tt >> 5, tid, t);
    } else if (bid < 4929) {              // fc1T (K=64, N=1024)
        int tt = bid - 4865; conv_t_dev(fc1_w, nullptr, fc1T, 64, 1024, tt & 31, tt >> 5, tid, t);
    } else if (bid < 4993) {              // fc2T (K=1024, N=64)
        int tt = bid - 4929; conv_t_dev(fc2_w, nullptr, fc2T, 1024, 64, tt & 1, tt >> 1, tid, t);
    } else if (bid < 5009) {              // wd2T
        int tt = bid - 4993; conv_t_dev(wq2, wk2, wd2T, 128, 128, tt & 3, tt >> 2, tid, t);
    } else if (bid < 5025) {              // gg1T
        int tt = bid - 5009; conv_t_dev(gg1_w, nullptr, gg1T, 128, 128, tt & 3, tt >> 2, tid, t);
    } else {                              // gg2T
        int tt = bid - 5025; conv_t_dev(gg2_w, nullptr, gg2T, 128, 128, tt & 3, tt >> 2, tid, t);
    }
}

// ---------------- generic 128x128 MFMA GEMM (+optional fused colsum) ----------
// OP: 0 none, 1 relu, 2 exp(x*scale). CS: write per-mtile column sums to pcs.
template <int OP, bool CS, typename OutT>
__global__ __launch_bounds__(256) void gemm_bf16(
    const __hip_bfloat16* __restrict__ A, const __hip_bfloat16* __restrict__ Bt,
    const float* __restrict__ bias, OutT* __restrict__ Co,
    int M, int Nn, int K, float scale, float* __restrict__ pcs)
{
    __shared__ __hip_bfloat16 As[128 * 32];
    __shared__ __hip_bfloat16 Bs[128 * 32];
    const int tid = threadIdx.x;
    const int wid = tid >> 6;
    const int lane = tid & 63;
    const int nwg = gridDim.x * gridDim.y;
    const int swz = xcd_swz(blockIdx.y * gridDim.x + blockIdx.x, nwg);
    const int bm = (swz >> 3) << 7, bn = (swz & 7) << 7;
    const int wm = (wid >> 1) << 6, wn = (wid & 1) << 6;

    f32x4 acc[4][4] = {};

    const int r0 = tid >> 2, c0 = (tid & 3) << 3;
    const int r1 = (tid + 256) >> 2, c1 = (tid & 3) << 3;
    __hip_bfloat16* lA0 = As + (size_t)(0 * 256 + (wid << 6)) * 8;
    __hip_bfloat16* lA1 = As + (size_t)(1 * 256 + (wid << 6)) * 8;
    __hip_bfloat16* lB0 = Bs + (size_t)(0 * 256 + (wid << 6)) * 8;
    __hip_bfloat16* lB1 = Bs + (size_t)(1 * 256 + (wid << 6)) * 8;

    const int arow = wm + (lane & 15);
    const int brow = wn + (lane & 15);
    const int kg = lane >> 4;

    for (int k0 = 0; k0 < K; k0 += 32) {
        GLOAD_LDS16(A + (long)(bm + r0) * K + k0 + c0, lA0);
        GLOAD_LDS16(A + (long)(bm + r1) * K + k0 + c1, lA1);
        GLOAD_LDS16(Bt + (long)(bn + r0) * K + k0 + c0, lB0);
        GLOAD_LDS16(Bt + (long)(bn + r1) * K + k0 + c1, lB1);
        __syncthreads();

        short8 af[4], bf_[4];
        #pragma unroll
        for (int m = 0; m < 4; ++m)
            af[m] = ((const short8*)As)[(arow + m * 16) * 4 + kg];
        #pragma unroll
        for (int n = 0; n < 4; ++n)
            bf_[n] = ((const short8*)Bs)[(brow + n * 16) * 4 + kg];
        #pragma unroll
        for (int m = 0; m < 4; ++m)
            #pragma unroll
            for (int n = 0; n < 4; ++n)
                acc[m][n] = __builtin_amdgcn_mfma_f32_16x16x32_bf16(
                    af[m], bf_[n], acc[m][n], 0, 0, 0);
        __syncthreads();
    }

    const int rq = (lane >> 4) << 2;
    float csum[4];
    #pragma unroll
    for (int n = 0; n < 4; ++n) {
        const int col = bn + wn + n * 16 + (lane & 15);
        const float bv = bias ? bias[col] : 0.f;
        csum[n] = 0.f;
        #pragma unroll
        for (int m = 0; m < 4; ++m) {
            #pragma unroll
            for (int j = 0; j < 4; ++j) {
                const int row = bm + wm + m * 16 + rq + j;
                float cv = acc[m][n][j] + bv;
                if (OP == 1) cv = fmaxf(cv, 0.f);
                if (OP == 2) cv = __expf(cv * scale);
                if (CS) csum[n] += cv;
                if constexpr (std::is_same<OutT, float>::value)
                    Co[(long)row * Nn + col] = cv;
                else
                    Co[(long)row * Nn + col] = __float2bfloat16(cv);
            }
        }
    }
    if (CS) {
        // per-column partial over this block's 128 rows: 8 thread-partials/col
        float* ps = (float*)As;  // [128 col_local][8 slot] = 4 KB (K-loop LDS dead)
        const int slot = ((wid >> 1) << 2) | (lane >> 4);
        #pragma unroll
        for (int n = 0; n < 4; ++n) {
            const int cl = wn + n * 16 + (lane & 15);
            ps[cl * 8 + slot] = csum[n];
        }
        __syncthreads();
        if (tid < 128) {
            float s = 0.f;
            #pragma unroll
            for (int q = 0; q < 8; ++q) s += ps[tid * 8 + q];
            pcs[(long)(swz >> 3) * 1024 + bn + tid] = s;
        }
    }
}

// ---------------- fused group-MLP chain ----------------
__global__ __launch_bounds__(256) void chain_k(
    const __hip_bfloat16* __restrict__ xb,
    const __hip_bfloat16* __restrict__ w1T,
    const __hip_bfloat16* __restrict__ w2T,
    const __hip_bfloat16* __restrict__ w3T,
    const float* __restrict__ b2, const float* __restrict__ b3,
    __hip_bfloat16* __restrict__ e1, float* __restrict__ pcs1)
{
    __shared__ unsigned short act[128 * 128];
    __shared__ unsigned short Wb[128 * 128];
    const int tid = threadIdx.x, wid = tid >> 6, lane = tid & 63;
    const int wm = (wid >> 1) << 6, wn = (wid & 1) << 6;
    const long tile = (long)blockIdx.x * (128 * 128);

    #pragma unroll
    for (int i = 0; i < 8; ++i) {
        int L = i * 256 + wid * 64 + lane;
        int r = L >> 4, c16o = (L & 15) ^ (r & 7);
        GLOAD_LDS16(xb + tile + r * 128 + c16o * 8,
                    (char*)act + (i * 256 + wid * 64) * 16);
        GLOAD_LDS16(w1T + r * 128 + c16o * 8,
                    (char*)Wb + (i * 256 + wid * 64) * 16);
    }
    __syncthreads();

    f32x4 acc[4][4];
    const int rq = (lane >> 4) << 2;

#define CHAIN_ZERO()                                                            \
    _Pragma("unroll") for (int m = 0; m < 4; ++m)                               \
        _Pragma("unroll") for (int n = 0; n < 4; ++n)                           \
            acc[m][n] = (f32x4){0.f, 0.f, 0.f, 0.f};

#define CHAIN_MM()                                                              \
    _Pragma("unroll") for (int ks = 0; ks < 4; ++ks) {                          \
        short8 af[4], bfv[4];                                                   \
        const int kc = ks * 4 + (lane >> 4);                                    \
        _Pragma("unroll") for (int m = 0; m < 4; ++m) {                         \
            int r = wm + m * 16 + (lane & 15);                                  \
            af[m] = *(const short8*)((const char*)act + swz16(r, kc) * 16);     \
        }                                                                       \
        _Pragma("unroll") for (int n = 0; n < 4; ++n) {                         \
            int r = wn + n * 16 + (lane & 15);                                  \
            bfv[n] = *(const short8*)((const char*)Wb + swz16(r, kc) * 16);     \
        }                                                                       \
        _Pragma("unroll") for (int m = 0; m < 4; ++m)                           \
            _Pragma("unroll") for (int n = 0; n < 4; ++n)                       \
                acc[m][n] = __builtin_amdgcn_mfma_f32_16x16x32_bf16(            \
                    af[m], bfv[n], acc[m][n], 0, 0, 0);                         \
    }

#define STAGE_W(wptr)                                                           \
    _Pragma("unroll") for (int i = 0; i < 8; ++i) {                             \
        int L = i * 256 + wid * 64 + lane;                                      \
        int r = L >> 4, c16o = (L & 15) ^ (r & 7);                              \
        GLOAD_LDS16((wptr) + r * 128 + c16o * 8,                                \
                    (char*)Wb + (i * 256 + wid * 64) * 16);                     \
    }

    CHAIN_ZERO(); CHAIN_MM();
    __syncthreads();
    STAGE_W(w2T);
    #pragma unroll
    for (int m = 0; m < 4; ++m)
        #pragma unroll
        for (int n = 0; n < 4; ++n)
            #pragma unroll
            for (int j = 0; j < 4; ++j) {
                int row = wm + m * 16 + rq + j, col = wn + n * 16 + (lane & 15);
                act[swz_elem(row, col)] = f2bf_bits(acc[m][n][j]);
            }
    __syncthreads();

    CHAIN_ZERO(); CHAIN_MM();
    __syncthreads();
    STAGE_W(w3T);
    {
        float bv[4];
        #pragma unroll
        for (int n = 0; n < 4; ++n) bv[n] = b2[wn + n * 16 + (lane & 15)];
        #pragma unroll
        for (int m = 0; m < 4; ++m)
            #pragma unroll
            for (int n = 0; n < 4; ++n)
                #pragma unroll
                for (int j = 0; j < 4; ++j) {
                    int row = wm + m * 16 + rq + j, col = wn + n * 16 + (lane & 15);
                    act[swz_elem(row, col)] = f2bf_bits(fmaxf(acc[m][n][j] + bv[n], 0.f));
                }
    }
    __syncthreads();

    CHAIN_ZERO(); CHAIN_MM();
    __syncthreads();
    {
        float bv[4];
        #pragma unroll
        for (int n = 0; n < 4; ++n) bv[n] = b3[wn + n * 16 + (lane & 15)];
        #pragma unroll
        for (int m = 0; m < 4; ++m)
            #pragma unroll
            for (int n = 0; n < 4; ++n)
                #pragma unroll
                for (int j = 0; j < 4; ++j) {
                    int row = wm + m * 16 + rq + j, col = wn + n * 16 + (lane & 15);
                    float ev = __expf((acc[m][n][j] + bv[n]) * 0.08838834764831845f);
                    act[swz_elem(row, col)] = f2bf_bits(ev);
                }
    }
    __syncthreads();

    #pragma unroll
    for (int i = 0; i < 8; ++i) {
        int idx = i * 256 + tid;
        int r = idx >> 4, c16o = idx & 15;
        short8 vd = *(const short8*)((const char*)act + swz16(r, c16o) * 16);
        *(short8*)((__hip_bfloat16*)e1 + tile + r * 128 + c16o * 8) = vd;
    }
    #pragma unroll
    for (int i = 0; i < 4; ++i) {
        int p = i * 256 + tid;
        int g = p >> 7, c = p & 127;
        float s = 0.f;
        #pragma unroll
        for (int t16 = 0; t16 < 16; ++t16) {
            int r = t16 * 8 + g;
            s += bf_bits2f(act[swz_elem(r, c)]);
        }
        pcs1[(long)blockIdx.x * 1024 + p] = s;
    }
#undef CHAIN_ZERO
#undef CHAIN_MM
#undef STAGE_W
}

// reduce: blocks 0-15 -> rcs1 (1024 partial rows), 16-31 -> rcs2 (16 rows)
__global__ void reduce_k(const float* __restrict__ pcs1, const float* __restrict__ pcs2,
                         float* __restrict__ rcs1, float* __restrict__ rcs2)
{
    __shared__ float red[4][64];
    const int tx = threadIdx.x, ty = threadIdx.y;
    if (blockIdx.x < 16) {
        const int col = blockIdx.x * 64 + tx;
        float s = 0.f;
        for (int p = ty; p < 1024; p += 4) s += pcs1[(long)p * 1024 + col];
        red[ty][tx] = s;
        __syncthreads();
        if (ty == 0)
            rcs1[col] = 1.f / (red[0][tx] + red[1][tx] + red[2][tx] + red[3][tx]);
    } else {
        const int col = (blockIdx.x - 16) * 64 + tx;
        float s = 0.f;
        for (int p = ty; p < 16; p += 4) s += pcs2[(long)p * 1024 + col];
        red[ty][tx] = s;
        __syncthreads();
        if (ty == 0)
            rcs2[col] = 1.f / (red[0][tx] + red[1][tx] + red[2][tx] + red[3][tx]);
    }
}

// ---------------- v-GEMM with fused single-chunk res epilogue ----------------
__global__ __launch_bounds__(256) void gemm_v_res(
    const __hip_bfloat16* __restrict__ A, const __hip_bfloat16* __restrict__ Bt,
    const __hip_bfloat16* __restrict__ e1, const __hip_bfloat16* __restrict__ e2,
    const float* __restrict__ rcs1, const float* __restrict__ rcs2,
    const float* __restrict__ invde, const float* __restrict__ feats,
    const float* __restrict__ lpe, __hip_bfloat16* __restrict__ res, int K)
{
    __shared__ __align__(16) char smem[128 * 136 * 2];   // 34816 B union
    __hip_bfloat16* As = (__hip_bfloat16*)smem;           // 8 KB (K-loop)
    __hip_bfloat16* Bs = (__hip_bfloat16*)(smem + 8192);  // 8 KB (K-loop)
    unsigned short* st = (unsigned short*)smem;           // [128][136] (epilogue)

    const int tid = threadIdx.x;
    const int wid = tid >> 6;
    const int lane = tid & 63;
    const int swz = xcd_swz(blockIdx.y * gridDim.x + blockIdx.x, gridDim.x * gridDim.y);
    const int bm = (swz >> 3) << 7, bn = (swz & 7) << 7;
    const int wm = (wid >> 1) << 6, wn = (wid & 1) << 6;

    f32x4 acc[4][4] = {};

    const int r0 = tid >> 2, c0s = (tid & 3) << 3;
    const int r1 = (tid + 256) >> 2;
    __hip_bfloat16* lA0 = As + (size_t)(0 * 256 + (wid << 6)) * 8;
    __hip_bfloat16* lA1 = As + (size_t)(1 * 256 + (wid << 6)) * 8;
    __hip_bfloat16* lB0 = Bs + (size_t)(0 * 256 + (wid << 6)) * 8;
    __hip_bfloat16* lB1 = Bs + (size_t)(1 * 256 + (wid << 6)) * 8;

    const int arow = wm + (lane & 15);
    const int brow = wn + (lane & 15);
    const int kg = lane >> 4;

    for (int k0 = 0; k0 < K; k0 += 32) {
        GLOAD_LDS16(A + (long)(bm + r0) * K + k0 + c0s, lA0);
        GLOAD_LDS16(A + (long)(bm + r1) * K + k0 + c0s, lA1);
        GLOAD_LDS16(Bt + (long)(bn + r0) * K + k0 + c0s, lB0);
        GLOAD_LDS16(Bt + (long)(bn + r1) * K + k0 + c0s, lB1);
        __syncthreads();

        short8 af[4], bf_[4];
        #pragma unroll
        for (int m = 0; m < 4; ++m)
            af[m] = ((const short8*)As)[(arow + m * 16) * 4 + kg];
        #pragma unroll
        for (int n = 0; n < 4; ++n)
            bf_[n] = ((const short8*)Bs)[(brow + n * 16) * 4 + kg];
        #pragma unroll
        for (int m = 0; m < 4; ++m)
            #pragma unroll
            for (int n = 0; n < 4; ++n)
                acc[m][n] = __builtin_amdgcn_mfma_f32_16x16x32_bf16(
                    af[m], bf_[n], acc[m][n], 0, 0, 0);
        __syncthreads();
    }

    // acc -> st (all 4 waves concurrently; K-loop LDS is dead after last barrier)
    const int rq = (lane >> 4) << 2;
    const int l15 = lane & 15;
    #pragma unroll
    for (int m = 0; m < 4; ++m)
        #pragma unroll
        for (int n = 0; n < 4; ++n)
            #pragma unroll
            for (int j = 0; j < 4; ++j)
                st[(wm + m * 16 + rq + j) * 136 + wn + n * 16 + l15] =
                    f2bf_bits(acc[m][n][j]);
    __syncthreads();

    const float lp = lpe[0];
    #pragma unroll
    for (int p = 0; p < 4; ++p) {
        const int r = p * 32 + (tid >> 3);
        const int cc = (tid & 7) << 4;
        const int grow = bm + r;
        const float angs = 100.f * feats[(long)grow * 64];
        const long goff = (long)grow * 1024 + bn + cc;
        const long goff2 = (long)(grow & 2047) * 1024 + bn + cc;
        short8 ev1[2], ev2[2], sv[2];
        ev1[0] = *(const short8*)((const unsigned short*)e1 + goff);
        ev1[1] = *(const short8*)((const unsigned short*)e1 + goff + 8);
        ev2[0] = *(const short8*)((const unsigned short*)e2 + goff2);
        ev2[1] = *(const short8*)((const unsigned short*)e2 + goff2 + 8);
        sv[0] = *(const short8*)&st[r * 136 + cc];
        sv[1] = *(const short8*)&st[r * 136 + cc + 8];
        unsigned short ov[16];
        #pragma unroll
        for (int q = 0; q < 16; ++q) {
            const int h = bn + cc + q;
            const float ang = angs * invde[h & 511];
            const float tr = (h < 512) ? __sinf(ang) : __cosf(ang);
            const float a = bf_bits2f((unsigned short)ev1[q >> 3][q & 7]) * rcs1[h] +
                            bf_bits2f((unsigned short)ev2[q >> 3][q & 7]) * rcs2[h];
            const float vv = bf_bits2f((unsigned short)sv[q >> 3][q & 7]);
            ov[q] = f2bf_bits(a * (vv + (tr + lp) * lp));
        }
        *(short8*)((unsigned short*)res + goff) = *(short8*)&ov[0];
        *(short8*)((unsigned short*)res + goff + 8) = *(short8*)&ov[8];
    }
}

// ---------------- out += res @ fc2_w  (split-K=2, atomicAdd fp32) -------------
// grid (2 kparts, 128 mtiles); out pre-initialized with features + fc2_b.
__global__ __launch_bounds__(256) void out_gemm_sk(
    const __hip_bfloat16* __restrict__ res, const __hip_bfloat16* __restrict__ fc2T,
    float* __restrict__ out)
{
    __shared__ __hip_bfloat16 As[128 * 32];  // 8 KB
    __shared__ __hip_bfloat16 Bs[64 * 32];   // 4 KB
    const int tid = threadIdx.x, wid = tid >> 6, lane = tid & 63;
    const int bm = blockIdx.y << 7;
    const int kbase = blockIdx.x << 9;       // 0 or 512
    const int wm = wid << 5;                 // 32 rows per wave

    f32x4 acc[2][4] = {};

    const int r0 = tid >> 2, c0 = (tid & 3) << 3;
    const int r1 = (tid + 256) >> 2;
    __hip_bfloat16* lA0 = As + (size_t)(0 * 256 + (wid << 6)) * 8;
    __hip_bfloat16* lA1 = As + (size_t)(1 * 256 + (wid << 6)) * 8;
    __hip_bfloat16* lB0 = Bs + (size_t)(0 * 256 + (wid << 6)) * 8;

    const int l15 = lane & 15;
    const int kg = lane >> 4;

    for (int k0 = 0; k0 < 512; k0 += 32) {
        GLOAD_LDS16(res + (long)(bm + r0) * 1024 + kbase + k0 + c0, lA0);
        GLOAD_LDS16(res + (long)(bm + r1) * 1024 + kbase + k0 + c0, lA1);
        GLOAD_LDS16(fc2T + (long)r0 * 1024 + kbase + k0 + c0, lB0);
        __syncthreads();

        short8 af[2], bf_[4];
        #pragma unroll
        for (int m = 0; m < 2; ++m)
            af[m] = ((const short8*)As)[(wm + m * 16 + l15) * 4 + kg];
        #pragma unroll
        for (int n = 0; n < 4; ++n)
            bf_[n] = ((const short8*)Bs)[(n * 16 + l15) * 4 + kg];
        #pragma unroll
        for (int m = 0; m < 2; ++m)
            #pragma unroll
            for (int n = 0; n < 4; ++n)
                acc[m][n] = __builtin_amdgcn_mfma_f32_16x16x32_bf16(
                    af[m], bf_[n], acc[m][n], 0, 0, 0);
        __syncthreads();
    }

    const int rq = (lane >> 4) << 2;
    #pragma unroll
    for (int n = 0; n < 4; ++n) {
        const int col = n * 16 + l15;
        #pragma unroll
        for (int m = 0; m < 2; ++m)
            #pragma unroll
            for (int j = 0; j < 4; ++j) {
                const int row = bm + wm + m * 16 + rq + j;
                atomicAdd(&out[(long)row * 64 + col], acc[m][n][j]);
            }
    }
}

extern "C" void kernel_launch(void* const* d_in, const int* in_sizes, int n_in,
                              void* d_out, int out_size, void* d_ws, size_t ws_size,
                              hipStream_t stream) {
    const float* features = (const float*)d_in[0];
    const float* fc1_w = (const float*)d_in[1];
    const float* fc1_b = (const float*)d_in[2];
    const float* fc2_w = (const float*)d_in[3];
    const float* fc2_b = (const float*)d_in[4];
    const float* g1_w = (const float*)d_in[5];
    const float* g1_b = (const float*)d_in[6];
    const float* g2_w = (const float*)d_in[7];
    const float* g2_b = (const float*)d_in[8];
    const float* gg1_w = (const float*)d_in[9];
    const float* gg1_b = (const float*)d_in[10];
    const float* gg2_w = (const float*)d_in[11];
    const float* gg2_b = (const float*)d_in[12];
    const float* wq = (const float*)d_in[13];
    const float* wk = (const float*)d_in[14];
    const float* wv = (const float*)d_in[15];
    const float* wq2 = (const float*)d_in[16];
    const float* wk2 = (const float*)d_in[17];
    const float* lpe = (const float*)d_in[18];
    float* out = (float*)d_out;

    char* ws = (char*)d_ws;
    const size_t MB = 1024ull * 1024ull;
    __hip_bfloat16* xb   = (__hip_bfloat16*)ws;                 // 32 MB
    __hip_bfloat16* e1   = (__hip_bfloat16*)(ws + 32 * MB);     // 32 MB
    __hip_bfloat16* resb = (__hip_bfloat16*)(ws + 64 * MB);     // 32 MB
    __hip_bfloat16* d2b  = (__hip_bfloat16*)(ws + 96 * MB);     // 4 MB
    __hip_bfloat16* t2b  = (__hip_bfloat16*)(ws + 100 * MB);    // 4 MB
    __hip_bfloat16* e2b  = (__hip_bfloat16*)(ws + 104 * MB);    // 4 MB
    float*          pcs1 = (float*)(ws + 108 * MB);             // 4 MB
    float*          pcs2 = (float*)(ws + 112 * MB);             // 64 KB (16x1024)
    char* W = ws + 113 * MB;
    __hip_bfloat16* featb = (__hip_bfloat16*)W;                 // 2 MB
    __hip_bfloat16* fc1T  = (__hip_bfloat16*)(W + 2 * MB);      // 128 KB
    __hip_bfloat16* wdT   = (__hip_bfloat16*)(W + 3 * MB);      // 2 MB
    __hip_bfloat16* wvT   = (__hip_bfloat16*)(W + 5 * MB);      // 2 MB
    __hip_bfloat16* g1T   = (__hip_bfloat16*)(W + 7 * MB);      // 2 MB
    __hip_bfloat16* g2T   = (__hip_bfloat16*)(W + 9 * MB);      // 2 MB
    __hip_bfloat16* fc2T  = (__hip_bfloat16*)(W + 11 * MB);     // 128 KB
    __hip_bfloat16* wd2T  = (__hip_bfloat16*)(W + 12 * MB);     // 32 KB
    __hip_bfloat16* gg1T  = (__hip_bfloat16*)(W + 12 * MB + 64 * 1024);
    __hip_bfloat16* gg2T  = (__hip_bfloat16*)(W + 12 * MB + 128 * 1024);
    float* rcs1  = (float*)(W + 13 * MB);                       // 4 KB
    float* rcs2  = rcs1 + 1024;
    float* invde = rcs2 + 1024;                                 // 512

    // 1. all prep in one launch (also out = features + fc2_b)
    prep_k<<<5041, 256, 0, stream>>>(
        features, fc1_w, fc2_w, fc2_b, g1_w, g2_w, wq, wk, wv, wq2, wk2,
        gg1_w, gg2_w, featb, fc1T, fc2T, wdT, wvT, g1T, g2T, wd2T, gg1T, gg2T,
        invde, out);

    // 2. x = features @ fc1_w + fc1_b
    gemm_bf16<0, false, __hip_bfloat16><<<dim3(8, 128), 256, 0, stream>>>(
        featb, fc1T, fc1_b, xb, 16384, 1024, 64, 0.f, nullptr);

    // 3. fused group chain -> e1 + pcs1
    chain_k<<<1024, 256, 0, stream>>>(xb, wd2T, gg1T, gg2T, gg1_b, gg2_b, e1, pcs1);

    // 4-6. tail branch (e2 GEMM fuses colsum partials)
    gemm_bf16<0, false, __hip_bfloat16><<<dim3(8, 16), 256, 0, stream>>>(
        xb + (size_t)14336 * 1024, wdT, nullptr, d2b, 2048, 1024, 1024, 0.f, nullptr);
    gemm_bf16<1, false, __hip_bfloat16><<<dim3(8, 16), 256, 0, stream>>>(
        d2b, g1T, g1_b, t2b, 2048, 1024, 1024, 0.f, nullptr);
    gemm_bf16<2, true, __hip_bfloat16><<<dim3(8, 16), 256, 0, stream>>>(
        t2b, g2T, g2_b, e2b, 2048, 1024, 1024, 0.03125f, pcs2);

    // 7. both softmax denominators -> reciprocals
    reduce_k<<<32, dim3(64, 4), 0, stream>>>(pcs1, pcs2, rcs1, rcs2);

    // 8. v-GEMM + fused res epilogue
    gemm_v_res<<<dim3(8, 128), 256, 0, stream>>>(
        xb, wvT, e1, e2b, rcs1, rcs2, invde, features, lpe, resb, 1024);

    // 9. out += res @ fc2_w   (split-K, atomics into pre-initialized out)
    out_gemm_sk<<<dim3(2, 128), 256, 0, stream>>>(resb, fc2T, out);
}

// Round 6
// 309.783 us; speedup vs baseline: 1.3846x; 1.2663x over previous
//
#include <hip/hip_runtime.h>
#include <hip/hip_bf16.h>
#include <math.h>
#include <type_traits>

// Round 6:
//  - gemm_v_res_out: v-GEMM (BK=64, XOR-swizzled LDS) + fused res epilogue +
//    fused out += res_tile @ fc2_w (mini-MFMA from LDS, atomicAdd fp32).
//    res never hits HBM. Kills out_gemm_sk + 64 MB traffic.
//  - tail GEMMs: BM=64 tiles -> 256-block grids (was 128 = half GPU idle).
//  - reduce_k: 1024-thread blocks.

typedef __attribute__((ext_vector_type(8))) short short8;
typedef __attribute__((ext_vector_type(4))) float f32x4;
typedef __attribute__((ext_vector_type(4))) float float4v;

#define GLOAD_LDS16(gptr, lptr)                                                 \
    __builtin_amdgcn_global_load_lds(                                           \
        (const __attribute__((address_space(1))) void*)(gptr),                  \
        (__attribute__((address_space(3))) void*)(lptr), 16, 0, 0)

static __device__ __forceinline__ unsigned short f2bf_bits(float v) {
    __hip_bfloat16 h = __float2bfloat16(v);
    return __builtin_bit_cast(unsigned short, h);
}
static __device__ __forceinline__ float bf_bits2f(unsigned short u) {
    return __bfloat162float(__builtin_bit_cast(__hip_bfloat16, u));
}
static __device__ __forceinline__ int swz16(int r, int c16) {
    return (r << 4) + (c16 ^ (r & 7));
}
static __device__ __forceinline__ int swz_elem(int r, int c) {
    return (r << 7) + ((((c << 1) ^ ((r & 7) << 4))) >> 1);
}
static __device__ __forceinline__ int xcd_swz(int bid, int nwg) {
    return (bid & 7) * (nwg >> 3) + (bid >> 3);
}

// ---------------- prep: everything small in one launch ----------------
static __device__ void conv_t_dev(const float* __restrict__ A, const float* __restrict__ Bsub,
                                  __hip_bfloat16* __restrict__ Ot, int K, int N,
                                  int bx, int by, int tid, float* t /* [32][33] */)
{
    const int n0 = bx * 32, k0 = by * 32;
    const int tx = tid & 31, ty = tid >> 5;
    #pragma unroll
    for (int j = 0; j < 4; ++j) {
        int k = k0 + ty + j * 8;
        float v = A[(long)k * N + n0 + tx];
        if (Bsub) v -= Bsub[(long)k * N + n0 + tx];
        t[(ty + j * 8) * 33 + tx] = v;
    }
    __syncthreads();
    #pragma unroll
    for (int j = 0; j < 4; ++j) {
        int n = n0 + ty + j * 8;
        Ot[(long)n * K + k0 + tx] = __float2bfloat16(t[tx * 33 + ty + j * 8]);
    }
}

__global__ __launch_bounds__(256) void prep_k(
    const float* __restrict__ features, const float* __restrict__ fc1_w,
    const float* __restrict__ fc2_w, const float* __restrict__ fc2_b,
    const float* __restrict__ g1_w, const float* __restrict__ g2_w,
    const float* __restrict__ wq, const float* __restrict__ wk,
    const float* __restrict__ wv, const float* __restrict__ wq2,
    const float* __restrict__ wk2, const float* __restrict__ gg1_w,
    const float* __restrict__ gg2_w,
    __hip_bfloat16* __restrict__ featb, __hip_bfloat16* __restrict__ fc1T,
    __hip_bfloat16* __restrict__ fc2T, __hip_bfloat16* __restrict__ wdT,
    __hip_bfloat16* __restrict__ wvT, __hip_bfloat16* __restrict__ g1T,
    __hip_bfloat16* __restrict__ g2T, __hip_bfloat16* __restrict__ wd2T,
    __hip_bfloat16* __restrict__ gg1T, __hip_bfloat16* __restrict__ gg2T,
    float* __restrict__ invde, float* __restrict__ out)
{
    __shared__ float t[32 * 33];
    const int bid = blockIdx.x;
    const int tid = threadIdx.x;

    if (bid == 0) {                       // invde LUT (512)
        #pragma unroll
        for (int i = 0; i < 2; ++i) {
            int idx = tid + i * 256;
            invde[idx] = exp2f(-9.96578428466209f * (float)idx * (1.f / 512.f));
        }
    } else if (bid < 257) {               // out = features + fc2_b  (1M fp32)
        const float4v* f4 = (const float4v*)features;
        float4v* o4 = (float4v*)out;
        const float4v* b4 = (const float4v*)fc2_b;
        long base = (long)(bid - 1) * 1024;
        #pragma unroll
        for (int i = 0; i < 4; ++i) {
            long idx = base + tid + i * 256;
            o4[idx] = f4[idx] + b4[idx & 15];
        }
    } else if (bid < 769) {               // features -> bf16 (1M elems, 8/thread)
        long j = (long)(bid - 257) * 256 + tid;
        const float4v* f4 = (const float4v*)features;
        float4v a = f4[j * 2], b = f4[j * 2 + 1];
        unsigned short o[8];
        #pragma unroll
        for (int q = 0; q < 4; ++q) { o[q] = f2bf_bits(a[q]); o[4 + q] = f2bf_bits(b[q]); }
        *(short8*)((unsigned short*)featb + j * 8) = *(short8*)o;
    } else if (bid < 1793) {              // wdT = (wq - wk)^T
        int tt = bid - 769;  conv_t_dev(wq, wk, wdT, 1024, 1024, tt & 31, tt >> 5, tid, t);
    } else if (bid < 2817) {              // wvT
        int tt = bid - 1793; conv_t_dev(wv, nullptr, wvT, 1024, 1024, tt & 31, tt >> 5, tid, t);
    } else if (bid < 3841) {              // g1T
        int tt = bid - 2817; conv_t_dev(g1_w, nullptr, g1T, 1024, 1024, tt & 31, tt >> 5, tid, t);
    } else if (bid < 4865) {              // g2T
        int tt = bid - 3841; conv_t_dev(g2_w, nullptr, g2T, 1024, 1024, tt & 31, tt >> 5, tid, t);
    } else if (bid < 4929) {              // fc1T (K=64, N=1024)
        int tt = bid - 4865; conv_t_dev(fc1_w, nullptr, fc1T, 64, 1024, tt & 31, tt >> 5, tid, t);
    } else if (bid < 4993) {              // fc2T (K=1024, N=64)
        int tt = bid - 4929; conv_t_dev(fc2_w, nullptr, fc2T, 1024, 64, tt & 1, tt >> 1, tid, t);
    } else if (bid < 5009) {              // wd2T
        int tt = bid - 4993; conv_t_dev(wq2, wk2, wd2T, 128, 128, tt & 3, tt >> 2, tid, t);
    } else if (bid < 5025) {              // gg1T
        int tt = bid - 5009; conv_t_dev(gg1_w, nullptr, gg1T, 128, 128, tt & 3, tt >> 2, tid, t);
    } else {                              // gg2T
        int tt = bid - 5025; conv_t_dev(gg2_w, nullptr, gg2T, 128, 128, tt & 3, tt >> 2, tid, t);
    }
}

// ---------------- 128x128 MFMA GEMM (x = features@fc1_w only now) ------------
template <int OP, typename OutT>
__global__ __launch_bounds__(256) void gemm_bf16(
    const __hip_bfloat16* __restrict__ A, const __hip_bfloat16* __restrict__ Bt,
    const float* __restrict__ bias, OutT* __restrict__ Co,
    int M, int Nn, int K, float scale)
{
    __shared__ __hip_bfloat16 As[128 * 32];
    __shared__ __hip_bfloat16 Bs[128 * 32];
    const int tid = threadIdx.x;
    const int wid = tid >> 6;
    const int lane = tid & 63;
    const int nwg = gridDim.x * gridDim.y;
    const int swz = xcd_swz(blockIdx.y * gridDim.x + blockIdx.x, nwg);
    const int bm = (swz >> 3) << 7, bn = (swz & 7) << 7;
    const int wm = (wid >> 1) << 6, wn = (wid & 1) << 6;

    f32x4 acc[4][4] = {};

    const int r0 = tid >> 2, c0 = (tid & 3) << 3;
    const int r1 = (tid + 256) >> 2;
    __hip_bfloat16* lA0 = As + (size_t)(0 * 256 + (wid << 6)) * 8;
    __hip_bfloat16* lA1 = As + (size_t)(1 * 256 + (wid << 6)) * 8;
    __hip_bfloat16* lB0 = Bs + (size_t)(0 * 256 + (wid << 6)) * 8;
    __hip_bfloat16* lB1 = Bs + (size_t)(1 * 256 + (wid << 6)) * 8;

    const int arow = wm + (lane & 15);
    const int brow = wn + (lane & 15);
    const int kg = lane >> 4;

    for (int k0 = 0; k0 < K; k0 += 32) {
        GLOAD_LDS16(A + (long)(bm + r0) * K + k0 + c0, lA0);
        GLOAD_LDS16(A + (long)(bm + r1) * K + k0 + c0, lA1);
        GLOAD_LDS16(Bt + (long)(bn + r0) * K + k0 + c0, lB0);
        GLOAD_LDS16(Bt + (long)(bn + r1) * K + k0 + c0, lB1);
        __syncthreads();

        short8 af[4], bf_[4];
        #pragma unroll
        for (int m = 0; m < 4; ++m)
            af[m] = ((const short8*)As)[(arow + m * 16) * 4 + kg];
        #pragma unroll
        for (int n = 0; n < 4; ++n)
            bf_[n] = ((const short8*)Bs)[(brow + n * 16) * 4 + kg];
        #pragma unroll
        for (int m = 0; m < 4; ++m)
            #pragma unroll
            for (int n = 0; n < 4; ++n)
                acc[m][n] = __builtin_amdgcn_mfma_f32_16x16x32_bf16(
                    af[m], bf_[n], acc[m][n], 0, 0, 0);
        __syncthreads();
    }

    const int rq = (lane >> 4) << 2;
    #pragma unroll
    for (int n = 0; n < 4; ++n) {
        const int col = bn + wn + n * 16 + (lane & 15);
        const float bv = bias ? bias[col] : 0.f;
        #pragma unroll
        for (int m = 0; m < 4; ++m) {
            #pragma unroll
            for (int j = 0; j < 4; ++j) {
                const int row = bm + wm + m * 16 + rq + j;
                float cv = acc[m][n][j] + bv;
                if (OP == 1) cv = fmaxf(cv, 0.f);
                if (OP == 2) cv = __expf(cv * scale);
                if constexpr (std::is_same<OutT, float>::value)
                    Co[(long)row * Nn + col] = cv;
                else
                    Co[(long)row * Nn + col] = __float2bfloat16(cv);
            }
        }
    }
}

// ---------------- 64x128 MFMA GEMM for the tail (full-GPU grids) -------------
// grid dim3(8, M/64). N = 1024. OP as above; CS: per-mtile colsums -> pcs.
template <int OP, bool CS>
__global__ __launch_bounds__(256) void gemm64(
    const __hip_bfloat16* __restrict__ A, const __hip_bfloat16* __restrict__ Bt,
    const float* __restrict__ bias, __hip_bfloat16* __restrict__ Co,
    int K, float scale, float* __restrict__ pcs)
{
    __shared__ __hip_bfloat16 As[64 * 32];    // 4 KB
    __shared__ __hip_bfloat16 Bs[128 * 32];   // 8 KB
    const int tid = threadIdx.x;
    const int wid = tid >> 6;
    const int lane = tid & 63;
    const int nwg = gridDim.x * gridDim.y;
    const int swz = xcd_swz(blockIdx.y * gridDim.x + blockIdx.x, nwg);
    const int bm = (swz >> 3) << 6, bn = (swz & 7) << 7;
    const int wm = (wid >> 1) << 5, wn = (wid & 1) << 6;  // wave tile 32x64

    f32x4 acc[2][4] = {};

    const int rA = tid >> 2, c0 = (tid & 3) << 3;
    const int rB0 = tid >> 2, rB1 = (tid + 256) >> 2;
    __hip_bfloat16* lA0 = As + (size_t)(wid << 6) * 8;
    __hip_bfloat16* lB0 = Bs + (size_t)(0 * 256 + (wid << 6)) * 8;
    __hip_bfloat16* lB1 = Bs + (size_t)(1 * 256 + (wid << 6)) * 8;

    const int l15 = lane & 15;
    const int kg = lane >> 4;
    const int arow = wm + l15;
    const int brow = wn + l15;

    for (int k0 = 0; k0 < K; k0 += 32) {
        GLOAD_LDS16(A + (long)(bm + rA) * K + k0 + c0, lA0);
        GLOAD_LDS16(Bt + (long)(bn + rB0) * K + k0 + c0, lB0);
        GLOAD_LDS16(Bt + (long)(bn + rB1) * K + k0 + c0, lB1);
        __syncthreads();

        short8 af[2], bf_[4];
        #pragma unroll
        for (int m = 0; m < 2; ++m)
            af[m] = ((const short8*)As)[(arow + m * 16) * 4 + kg];
        #pragma unroll
        for (int n = 0; n < 4; ++n)
            bf_[n] = ((const short8*)Bs)[(brow + n * 16) * 4 + kg];
        #pragma unroll
        for (int m = 0; m < 2; ++m)
            #pragma unroll
            for (int n = 0; n < 4; ++n)
                acc[m][n] = __builtin_amdgcn_mfma_f32_16x16x32_bf16(
                    af[m], bf_[n], acc[m][n], 0, 0, 0);
        __syncthreads();
    }

    const int rq = (lane >> 4) << 2;
    float csum[4];
    #pragma unroll
    for (int n = 0; n < 4; ++n) {
        const int col = bn + wn + n * 16 + l15;
        const float bv = bias ? bias[col] : 0.f;
        csum[n] = 0.f;
        #pragma unroll
        for (int m = 0; m < 2; ++m) {
            #pragma unroll
            for (int j = 0; j < 4; ++j) {
                const int row = bm + wm + m * 16 + rq + j;
                float cv = acc[m][n][j] + bv;
                if (OP == 1) cv = fmaxf(cv, 0.f);
                if (OP == 2) cv = __expf(cv * scale);
                if (CS) csum[n] += cv;
                Co[(long)row * 1024 + col] = __float2bfloat16(cv);
            }
        }
    }
    if (CS) {
        __syncthreads();
        float* ps = (float*)As;  // [128 col_local][8 slot] = 4 KB
        const int slot = ((wid >> 1) << 2) | kg;
        #pragma unroll
        for (int n = 0; n < 4; ++n)
            ps[(wn + n * 16 + l15) * 8 + slot] = csum[n];
        __syncthreads();
        if (tid < 128) {
            float s = 0.f;
            #pragma unroll
            for (int q = 0; q < 8; ++q) s += ps[tid * 8 + q];
            pcs[(long)(swz >> 3) * 1024 + bn + tid] = s;
        }
    }
}

// ---------------- fused group-MLP chain (unchanged) ----------------
__global__ __launch_bounds__(256) void chain_k(
    const __hip_bfloat16* __restrict__ xb,
    const __hip_bfloat16* __restrict__ w1T,
    const __hip_bfloat16* __restrict__ w2T,
    const __hip_bfloat16* __restrict__ w3T,
    const float* __restrict__ b2, const float* __restrict__ b3,
    __hip_bfloat16* __restrict__ e1, float* __restrict__ pcs1)
{
    __shared__ unsigned short act[128 * 128];
    __shared__ unsigned short Wb[128 * 128];
    const int tid = threadIdx.x, wid = tid >> 6, lane = tid & 63;
    const int wm = (wid >> 1) << 6, wn = (wid & 1) << 6;
    const long tile = (long)blockIdx.x * (128 * 128);

    #pragma unroll
    for (int i = 0; i < 8; ++i) {
        int L = i * 256 + wid * 64 + lane;
        int r = L >> 4, c16o = (L & 15) ^ (r & 7);
        GLOAD_LDS16(xb + tile + r * 128 + c16o * 8,
                    (char*)act + (i * 256 + wid * 64) * 16);
        GLOAD_LDS16(w1T + r * 128 + c16o * 8,
                    (char*)Wb + (i * 256 + wid * 64) * 16);
    }
    __syncthreads();

    f32x4 acc[4][4];
    const int rq = (lane >> 4) << 2;

#define CHAIN_ZERO()                                                            \
    _Pragma("unroll") for (int m = 0; m < 4; ++m)                               \
        _Pragma("unroll") for (int n = 0; n < 4; ++n)                           \
            acc[m][n] = (f32x4){0.f, 0.f, 0.f, 0.f};

#define CHAIN_MM()                                                              \
    _Pragma("unroll") for (int ks = 0; ks < 4; ++ks) {                          \
        short8 af[4], bfv[4];                                                   \
        const int kc = ks * 4 + (lane >> 4);                                    \
        _Pragma("unroll") for (int m = 0; m < 4; ++m) {                         \
            int r = wm + m * 16 + (lane & 15);                                  \
            af[m] = *(const short8*)((const char*)act + swz16(r, kc) * 16);     \
        }                                                                       \
        _Pragma("unroll") for (int n = 0; n < 4; ++n) {                         \
            int r = wn + n * 16 + (lane & 15);                                  \
            bfv[n] = *(const short8*)((const char*)Wb + swz16(r, kc) * 16);     \
        }                                                                       \
        _Pragma("unroll") for (int m = 0; m < 4; ++m)                           \
            _Pragma("unroll") for (int n = 0; n < 4; ++n)                       \
                acc[m][n] = __builtin_amdgcn_mfma_f32_16x16x32_bf16(            \
                    af[m], bfv[n], acc[m][n], 0, 0, 0);                         \
    }

#define STAGE_W(wptr)                                                           \
    _Pragma("unroll") for (int i = 0; i < 8; ++i) {                             \
        int L = i * 256 + wid * 64 + lane;                                      \
        int r = L >> 4, c16o = (L & 15) ^ (r & 7);                              \
        GLOAD_LDS16((wptr) + r * 128 + c16o * 8,                                \
                    (char*)Wb + (i * 256 + wid * 64) * 16);                     \
    }

    CHAIN_ZERO(); CHAIN_MM();
    __syncthreads();
    STAGE_W(w2T);
    #pragma unroll
    for (int m = 0; m < 4; ++m)
        #pragma unroll
        for (int n = 0; n < 4; ++n)
            #pragma unroll
            for (int j = 0; j < 4; ++j) {
                int row = wm + m * 16 + rq + j, col = wn + n * 16 + (lane & 15);
                act[swz_elem(row, col)] = f2bf_bits(acc[m][n][j]);
            }
    __syncthreads();

    CHAIN_ZERO(); CHAIN_MM();
    __syncthreads();
    STAGE_W(w3T);
    {
        float bv[4];
        #pragma unroll
        for (int n = 0; n < 4; ++n) bv[n] = b2[wn + n * 16 + (lane & 15)];
        #pragma unroll
        for (int m = 0; m < 4; ++m)
            #pragma unroll
            for (int n = 0; n < 4; ++n)
                #pragma unroll
                for (int j = 0; j < 4; ++j) {
                    int row = wm + m * 16 + rq + j, col = wn + n * 16 + (lane & 15);
                    act[swz_elem(row, col)] = f2bf_bits(fmaxf(acc[m][n][j] + bv[n], 0.f));
                }
    }
    __syncthreads();

    CHAIN_ZERO(); CHAIN_MM();
    __syncthreads();
    {
        float bv[4];
        #pragma unroll
        for (int n = 0; n < 4; ++n) bv[n] = b3[wn + n * 16 + (lane & 15)];
        #pragma unroll
        for (int m = 0; m < 4; ++m)
            #pragma unroll
            for (int n = 0; n < 4; ++n)
                #pragma unroll
                for (int j = 0; j < 4; ++j) {
                    int row = wm + m * 16 + rq + j, col = wn + n * 16 + (lane & 15);
                    float ev = __expf((acc[m][n][j] + bv[n]) * 0.08838834764831845f);
                    act[swz_elem(row, col)] = f2bf_bits(ev);
                }
    }
    __syncthreads();

    #pragma unroll
    for (int i = 0; i < 8; ++i) {
        int idx = i * 256 + tid;
        int r = idx >> 4, c16o = idx & 15;
        short8 vd = *(const short8*)((const char*)act + swz16(r, c16o) * 16);
        *(short8*)((__hip_bfloat16*)e1 + tile + r * 128 + c16o * 8) = vd;
    }
    #pragma unroll
    for (int i = 0; i < 4; ++i) {
        int p = i * 256 + tid;
        int g = p >> 7, c = p & 127;
        float s = 0.f;
        #pragma unroll
        for (int t16 = 0; t16 < 16; ++t16) {
            int r = t16 * 8 + g;
            s += bf_bits2f(act[swz_elem(r, c)]);
        }
        pcs1[(long)blockIdx.x * 1024 + p] = s;
    }
#undef CHAIN_ZERO
#undef CHAIN_MM
#undef STAGE_W
}

// reduce: blocks 0-15 -> rcs1 (1024 rows), 16-31 -> rcs2 (32 rows). block (64,16)
__global__ void reduce_k(const float* __restrict__ pcs1, const float* __restrict__ pcs2,
                         float* __restrict__ rcs1, float* __restrict__ rcs2)
{
    __shared__ float red[16][64];
    const int tx = threadIdx.x, ty = threadIdx.y;
    if (blockIdx.x < 16) {
        const int col = blockIdx.x * 64 + tx;
        float s = 0.f;
        for (int p = ty; p < 1024; p += 16) s += pcs1[(long)p * 1024 + col];
        red[ty][tx] = s;
        __syncthreads();
        if (ty == 0) {
            float t = 0.f;
            #pragma unroll
            for (int q = 0; q < 16; ++q) t += red[q][tx];
            rcs1[col] = 1.f / t;
        }
    } else {
        const int col = (blockIdx.x - 16) * 64 + tx;
        float s = 0.f;
        for (int p = ty; p < 32; p += 16) s += pcs2[(long)p * 1024 + col];
        red[ty][tx] = s;
        __syncthreads();
        if (ty == 0) {
            float t = 0.f;
            #pragma unroll
            for (int q = 0; q < 16; ++q) t += red[q][tx];
            rcs2[col] = 1.f / t;
        }
    }
}

// ------ v-GEMM (BK=64, swizzled) + fused res epilogue + fused out-accum ------
__global__ __launch_bounds__(256) void gemm_v_res_out(
    const __hip_bfloat16* __restrict__ A, const __hip_bfloat16* __restrict__ Bt,
    const __hip_bfloat16* __restrict__ e1, const __hip_bfloat16* __restrict__ e2,
    const float* __restrict__ rcs1, const float* __restrict__ rcs2,
    const float* __restrict__ invde, const float* __restrict__ feats,
    const float* __restrict__ lpe, const __hip_bfloat16* __restrict__ fc2T,
    float* __restrict__ out, int K)
{
    __shared__ __align__(16) char smem[34816];            // st[128][136] union
    __hip_bfloat16* As = (__hip_bfloat16*)smem;           // 16 KB [128][64]
    __hip_bfloat16* Bs = (__hip_bfloat16*)(smem + 16384); // 16 KB [128][64]
    unsigned short* st = (unsigned short*)smem;           // [128][136] (epilogue)

    const int tid = threadIdx.x;
    const int wid = tid >> 6;
    const int lane = tid & 63;
    const int swz = xcd_swz(blockIdx.y * gridDim.x + blockIdx.x, gridDim.x * gridDim.y);
    const int bm = (swz >> 3) << 7, bn = (swz & 7) << 7;
    const int wm = (wid >> 1) << 6, wn = (wid & 1) << 6;

    f32x4 acc[4][4] = {};

    // staging: 4 insts/matrix; idx = i*256+tid; r = idx>>3, c8 = tid&7,
    // swizzled global col c8s = c8 ^ (r&7); LDS dest linear [r][c8].
    const int c8 = tid & 7;
    const int l15 = lane & 15;
    const int kg = lane >> 4;
    const int arow = wm + l15;
    const int brow = wn + l15;

    for (int k0 = 0; k0 < K; k0 += 64) {
        #pragma unroll
        for (int i = 0; i < 4; ++i) {
            const int r = i * 32 + (tid >> 3);
            const int c8s = c8 ^ (r & 7);
            GLOAD_LDS16(A + (long)(bm + r) * K + k0 + c8s * 8,
                        (char*)As + (i * 256 + wid * 64) * 16);
            GLOAD_LDS16(Bt + (long)(bn + r) * K + k0 + c8s * 8,
                        (char*)Bs + (i * 256 + wid * 64) * 16);
        }
        __syncthreads();

        #pragma unroll
        for (int ks2 = 0; ks2 < 2; ++ks2) {
            const int kslot = ks2 * 4 + kg;
            short8 af[4], bf_[4];
            #pragma unroll
            for (int m = 0; m < 4; ++m) {
                const int r = arow + m * 16;
                af[m] = *(const short8*)(As + (r * 8 + (kslot ^ (r & 7))) * 8);
            }
            #pragma unroll
            for (int n = 0; n < 4; ++n) {
                const int r = brow + n * 16;
                bf_[n] = *(const short8*)(Bs + (r * 8 + (kslot ^ (r & 7))) * 8);
            }
            #pragma unroll
            for (int m = 0; m < 4; ++m)
                #pragma unroll
                for (int n = 0; n < 4; ++n)
                    acc[m][n] = __builtin_amdgcn_mfma_f32_16x16x32_bf16(
                        af[m], bf_[n], acc[m][n], 0, 0, 0);
        }
        __syncthreads();
    }

    // v tile -> st (bf16)
    const int rq = (lane >> 4) << 2;
    #pragma unroll
    for (int m = 0; m < 4; ++m)
        #pragma unroll
        for (int n = 0; n < 4; ++n)
            #pragma unroll
            for (int j = 0; j < 4; ++j)
                st[(wm + m * 16 + rq + j) * 136 + wn + n * 16 + l15] =
                    f2bf_bits(acc[m][n][j]);
    __syncthreads();

    // res = (e1*rcs1 + e2*rcs2) * (v + pe)  -> st in place (vectorized)
    const float lp = lpe[0];
    #pragma unroll
    for (int p = 0; p < 4; ++p) {
        const int r = p * 32 + (tid >> 3);
        const int cc = (tid & 7) << 4;
        const int grow = bm + r;
        const float angs = 100.f * feats[(long)grow * 64];
        const long goff = (long)grow * 1024 + bn + cc;
        const long goff2 = (long)(grow & 2047) * 1024 + bn + cc;
        short8 ev1[2], ev2[2], sv[2];
        ev1[0] = *(const short8*)((const unsigned short*)e1 + goff);
        ev1[1] = *(const short8*)((const unsigned short*)e1 + goff + 8);
        ev2[0] = *(const short8*)((const unsigned short*)e2 + goff2);
        ev2[1] = *(const short8*)((const unsigned short*)e2 + goff2 + 8);
        sv[0] = *(const short8*)&st[r * 136 + cc];
        sv[1] = *(const short8*)&st[r * 136 + cc + 8];
        unsigned short ov[16];
        #pragma unroll
        for (int q = 0; q < 16; ++q) {
            const int h = bn + cc + q;
            const float ang = angs * invde[h & 511];
            const float tr = (h < 512) ? __sinf(ang) : __cosf(ang);
            const float a = bf_bits2f((unsigned short)ev1[q >> 3][q & 7]) * rcs1[h] +
                            bf_bits2f((unsigned short)ev2[q >> 3][q & 7]) * rcs2[h];
            const float vv = bf_bits2f((unsigned short)sv[q >> 3][q & 7]);
            ov[q] = f2bf_bits(a * (vv + (tr + lp) * lp));
        }
        *(short8*)&st[r * 136 + cc] = *(short8*)&ov[0];
        *(short8*)&st[r * 136 + cc + 8] = *(short8*)&ov[8];
    }
    __syncthreads();

    // out[bm..bm+128, 0..64] += res_tile @ fc2_w[bn..bn+128, :]
    // A = st [128][136]; B rows = out-cols from fc2T[oc][bn + k]. Wave: 32 rows.
    {
        const int wmO = wid << 5;
        f32x4 aco[2][4] = {};
        #pragma unroll
        for (int ks = 0; ks < 4; ++ks) {
            short8 afo[2], bfo[4];
            #pragma unroll
            for (int m = 0; m < 2; ++m)
                afo[m] = *(const short8*)&st[(wmO + m * 16 + l15) * 136 + ks * 32 + kg * 8];
            #pragma unroll
            for (int n = 0; n < 4; ++n)
                bfo[n] = *(const short8*)((const unsigned short*)fc2T +
                                          (long)(n * 16 + l15) * 1024 + bn + ks * 32 + kg * 8);
            #pragma unroll
            for (int m = 0; m < 2; ++m)
                #pragma unroll
                for (int n = 0; n < 4; ++n)
                    aco[m][n] = __builtin_amdgcn_mfma_f32_16x16x32_bf16(
                        afo[m], bfo[n], aco[m][n], 0, 0, 0);
        }
        #pragma unroll
        for (int m = 0; m < 2; ++m)
            #pragma unroll
            for (int n = 0; n < 4; ++n)
                #pragma unroll
                for (int j = 0; j < 4; ++j) {
                    const int row = bm + wmO + m * 16 + rq + j;
                    atomicAdd(&out[(long)row * 64 + n * 16 + l15], aco[m][n][j]);
                }
    }
}

extern "C" void kernel_launch(void* const* d_in, const int* in_sizes, int n_in,
                              void* d_out, int out_size, void* d_ws, size_t ws_size,
                              hipStream_t stream) {
    const float* features = (const float*)d_in[0];
    const float* fc1_w = (const float*)d_in[1];
    const float* fc1_b = (const float*)d_in[2];
    const float* fc2_w = (const float*)d_in[3];
    const float* fc2_b = (const float*)d_in[4];
    const float* g1_w = (const float*)d_in[5];
    const float* g1_b = (const float*)d_in[6];
    const float* g2_w = (const float*)d_in[7];
    const float* g2_b = (const float*)d_in[8];
    const float* gg1_w = (const float*)d_in[9];
    const float* gg1_b = (const float*)d_in[10];
    const float* gg2_w = (const float*)d_in[11];
    const float* gg2_b = (const float*)d_in[12];
    const float* wq = (const float*)d_in[13];
    const float* wk = (const float*)d_in[14];
    const float* wv = (const float*)d_in[15];
    const float* wq2 = (const float*)d_in[16];
    const float* wk2 = (const float*)d_in[17];
    const float* lpe = (const float*)d_in[18];
    float* out = (float*)d_out;

    char* ws = (char*)d_ws;
    const size_t MB = 1024ull * 1024ull;
    __hip_bfloat16* xb   = (__hip_bfloat16*)ws;                 // 32 MB
    __hip_bfloat16* e1   = (__hip_bfloat16*)(ws + 32 * MB);     // 32 MB
    __hip_bfloat16* d2b  = (__hip_bfloat16*)(ws + 64 * MB);     // 4 MB
    __hip_bfloat16* t2b  = (__hip_bfloat16*)(ws + 68 * MB);     // 4 MB
    __hip_bfloat16* e2b  = (__hip_bfloat16*)(ws + 72 * MB);     // 4 MB
    float*          pcs1 = (float*)(ws + 76 * MB);              // 4 MB (1024x1024)
    float*          pcs2 = (float*)(ws + 80 * MB);              // 128 KB (32x1024)
    char* W = ws + 81 * MB;
    __hip_bfloat16* featb = (__hip_bfloat16*)W;                 // 2 MB
    __hip_bfloat16* fc1T  = (__hip_bfloat16*)(W + 2 * MB);      // 128 KB
    __hip_bfloat16* wdT   = (__hip_bfloat16*)(W + 3 * MB);      // 2 MB
    __hip_bfloat16* wvT   = (__hip_bfloat16*)(W + 5 * MB);      // 2 MB
    __hip_bfloat16* g1T   = (__hip_bfloat16*)(W + 7 * MB);      // 2 MB
    __hip_bfloat16* g2T   = (__hip_bfloat16*)(W + 9 * MB);      // 2 MB
    __hip_bfloat16* fc2T  = (__hip_bfloat16*)(W + 11 * MB);     // 128 KB
    __hip_bfloat16* wd2T  = (__hip_bfloat16*)(W + 12 * MB);     // 32 KB
    __hip_bfloat16* gg1T  = (__hip_bfloat16*)(W + 12 * MB + 64 * 1024);
    __hip_bfloat16* gg2T  = (__hip_bfloat16*)(W + 12 * MB + 128 * 1024);
    float* rcs1  = (float*)(W + 13 * MB);                       // 4 KB
    float* rcs2  = rcs1 + 1024;
    float* invde = rcs2 + 1024;                                 // 512

    // 1. all prep (also out = features + fc2_b)
    prep_k<<<5041, 256, 0, stream>>>(
        features, fc1_w, fc2_w, fc2_b, g1_w, g2_w, wq, wk, wv, wq2, wk2,
        gg1_w, gg2_w, featb, fc1T, fc2T, wdT, wvT, g1T, g2T, wd2T, gg1T, gg2T,
        invde, out);

    // 2. x = features @ fc1_w + fc1_b
    gemm_bf16<0, __hip_bfloat16><<<dim3(8, 128), 256, 0, stream>>>(
        featb, fc1T, fc1_b, xb, 16384, 1024, 64, 0.f);

    // 3. fused group chain -> e1 + pcs1
    chain_k<<<1024, 256, 0, stream>>>(xb, wd2T, gg1T, gg2T, gg1_b, gg2_b, e1, pcs1);

    // 4-6. tail branch, 64-row tiles (256-block grids)
    gemm64<0, false><<<dim3(8, 32), 256, 0, stream>>>(
        xb + (size_t)14336 * 1024, wdT, nullptr, d2b, 1024, 0.f, nullptr);
    gemm64<1, false><<<dim3(8, 32), 256, 0, stream>>>(
        d2b, g1T, g1_b, t2b, 1024, 0.f, nullptr);
    gemm64<2, true><<<dim3(8, 32), 256, 0, stream>>>(
        t2b, g2T, g2_b, e2b, 1024, 0.03125f, pcs2);

    // 7. both softmax denominators -> reciprocals
    reduce_k<<<32, dim3(64, 16), 0, stream>>>(pcs1, pcs2, rcs1, rcs2);

    // 8. v-GEMM + res epilogue + out-accum (res never hits HBM)
    gemm_v_res_out<<<dim3(8, 128), 256, 0, stream>>>(
        xb, wvT, e1, e2b, rcs1, rcs2, invde, features, lpe, fc2T, out, 1024);
}

// Round 7
// 297.794 us; speedup vs baseline: 1.4403x; 1.0403x over previous
//
#include <hip/hip_runtime.h>
#include <hip/hip_bf16.h>
#include <math.h>
#include <type_traits>

// Round 7:
//  - T4 counted-vmcnt double-buffered K-loops (raw s_barrier + vmcnt(N), never
//    drain-0 mid-loop) in gemm_v_res_out (BK=64) and gemm64 (BK=32). T5 setprio.
//  - x-GEMM reads fp32 features/fc1_w directly (reg-stage+convert) -> merged
//    into prep launch; featb/fc1T dead.
//  - chain_k + tail-GEMM-1 merged into one launch (mid_k).
//  Launches: prep+x, mid(chain+tail1), tail2, tail3, reduce, v_res_out = 6.

typedef __attribute__((ext_vector_type(8))) short short8;
typedef __attribute__((ext_vector_type(4))) float f32x4;
typedef __attribute__((ext_vector_type(4))) float float4v;

#define GLOAD_LDS16(gptr, lptr)                                                 \
    __builtin_amdgcn_global_load_lds(                                           \
        (const __attribute__((address_space(1))) void*)(gptr),                  \
        (__attribute__((address_space(3))) void*)(lptr), 16, 0, 0)

static __device__ __forceinline__ unsigned short f2bf_bits(float v) {
    __hip_bfloat16 h = __float2bfloat16(v);
    return __builtin_bit_cast(unsigned short, h);
}
static __device__ __forceinline__ float bf_bits2f(unsigned short u) {
    return __bfloat162float(__builtin_bit_cast(__hip_bfloat16, u));
}
static __device__ __forceinline__ int swz16(int r, int c16) {
    return (r << 4) + (c16 ^ (r & 7));
}
static __device__ __forceinline__ int swz_elem(int r, int c) {
    return (r << 7) + ((((c << 1) ^ ((r & 7) << 4))) >> 1);
}
static __device__ __forceinline__ int xcd_swz(int bid, int nwg) {
    return (bid & 7) * (nwg >> 3) + (bid >> 3);
}

// ---------------- prep + x-GEMM in one launch ----------------
static __device__ void conv_t_dev(const float* __restrict__ A, const float* __restrict__ Bsub,
                                  __hip_bfloat16* __restrict__ Ot, int K, int N,
                                  int bx, int by, int tid, float* t /* [32][33] */)
{
    const int n0 = bx * 32, k0 = by * 32;
    const int tx = tid & 31, ty = tid >> 5;
    #pragma unroll
    for (int j = 0; j < 4; ++j) {
        int k = k0 + ty + j * 8;
        float v = A[(long)k * N + n0 + tx];
        if (Bsub) v -= Bsub[(long)k * N + n0 + tx];
        t[(ty + j * 8) * 33 + tx] = v;
    }
    __syncthreads();
    #pragma unroll
    for (int j = 0; j < 4; ++j) {
        int n = n0 + ty + j * 8;
        Ot[(long)n * K + k0 + tx] = __float2bfloat16(t[tx * 33 + ty + j * 8]);
    }
}

// x[bm:+128][bn:+128] = features(fp32)[128x64] @ fc1_w(fp32)[64x1024] + fc1_b
static __device__ void xgemm_dev(const float* __restrict__ features,
                                 const float* __restrict__ fc1_w,
                                 const float* __restrict__ fc1_b,
                                 __hip_bfloat16* __restrict__ xb,
                                 int tile, int tid, char* smem)
{
    unsigned short* As = (unsigned short*)smem;            // [128][64] swizzled
    unsigned short* Bs = (unsigned short*)(smem + 16384);  // [128 n][64 k] swizzled
    const int bm = (tile >> 3) << 7, bn = (tile & 7) << 7;
    const int wid = tid >> 6, lane = tid & 63;
    const int wm = (wid >> 1) << 6, wn = (wid & 1) << 6;
    const int l15 = lane & 15, kg = lane >> 4;

    // stage A (convert fp32->bf16, swizzled)
    #pragma unroll
    for (int i = 0; i < 8; ++i) {
        int idx = i * 256 + tid;          // [0,2048) float4 granules
        int r = idx >> 4, c4 = idx & 15;
        float4v f = *(const float4v*)(features + (long)(bm + r) * 64 + c4 * 4);
        unsigned int p0 = f2bf_bits(f[0]) | ((unsigned int)f2bf_bits(f[1]) << 16);
        unsigned int p1 = f2bf_bits(f[2]) | ((unsigned int)f2bf_bits(f[3]) << 16);
        int dst = r * 64 + (((c4 >> 1) ^ (r & 7)) << 3) + (c4 & 1) * 4;
        unsigned int* p = (unsigned int*)&As[dst];
        p[0] = p0; p[1] = p1;
    }
    // stage B transposed: Bs[n][k] = fc1_w[k][bn+n]
    #pragma unroll
    for (int i = 0; i < 8; ++i) {
        int idx = i * 256 + tid;          // [0,2048)
        int k = idx >> 5, c4b = idx & 31;
        float4v g = *(const float4v*)(fc1_w + (long)k * 1024 + bn + c4b * 4);
        #pragma unroll
        for (int q = 0; q < 4; ++q) {
            int n = c4b * 4 + q;
            Bs[n * 64 + (((k >> 3) ^ (n & 7)) << 3) + (k & 7)] = f2bf_bits(g[q]);
        }
    }
    __syncthreads();

    f32x4 acc[4][4] = {};
    #pragma unroll
    for (int ks2 = 0; ks2 < 2; ++ks2) {
        const int kslot = ks2 * 4 + kg;
        short8 af[4], bf_[4];
        #pragma unroll
        for (int m = 0; m < 4; ++m) {
            int r = wm + m * 16 + l15;
            af[m] = *(const short8*)&As[r * 64 + ((kslot ^ (r & 7)) << 3)];
        }
        #pragma unroll
        for (int n = 0; n < 4; ++n) {
            int r = wn + n * 16 + l15;
            bf_[n] = *(const short8*)&Bs[r * 64 + ((kslot ^ (r & 7)) << 3)];
        }
        #pragma unroll
        for (int m = 0; m < 4; ++m)
            #pragma unroll
            for (int n = 0; n < 4; ++n)
                acc[m][n] = __builtin_amdgcn_mfma_f32_16x16x32_bf16(
                    af[m], bf_[n], acc[m][n], 0, 0, 0);
    }
    const int rq = kg << 2;
    #pragma unroll
    for (int n = 0; n < 4; ++n) {
        const int col = bn + wn + n * 16 + l15;
        const float bv = fc1_b[col];
        #pragma unroll
        for (int m = 0; m < 4; ++m)
            #pragma unroll
            for (int j = 0; j < 4; ++j)
                xb[(long)(bm + wm + m * 16 + rq + j) * 1024 + col] =
                    __float2bfloat16(acc[m][n][j] + bv);
    }
}

__global__ __launch_bounds__(256) void prep_x_k(
    const float* __restrict__ features, const float* __restrict__ fc1_w,
    const float* __restrict__ fc1_b, const float* __restrict__ fc2_w,
    const float* __restrict__ fc2_b, const float* __restrict__ g1_w,
    const float* __restrict__ g2_w, const float* __restrict__ wq,
    const float* __restrict__ wk, const float* __restrict__ wv,
    const float* __restrict__ wq2, const float* __restrict__ wk2,
    const float* __restrict__ gg1_w, const float* __restrict__ gg2_w,
    __hip_bfloat16* __restrict__ fc2T, __hip_bfloat16* __restrict__ wdT,
    __hip_bfloat16* __restrict__ wvT, __hip_bfloat16* __restrict__ g1T,
    __hip_bfloat16* __restrict__ g2T, __hip_bfloat16* __restrict__ wd2T,
    __hip_bfloat16* __restrict__ gg1T, __hip_bfloat16* __restrict__ gg2T,
    __hip_bfloat16* __restrict__ xb, float* __restrict__ invde,
    float* __restrict__ out)
{
    __shared__ __align__(16) char smem[32768];
    float* t = (float*)smem;
    const int bid = blockIdx.x;
    const int tid = threadIdx.x;

    if (bid == 0) {
        #pragma unroll
        for (int i = 0; i < 2; ++i) {
            int idx = tid + i * 256;
            invde[idx] = exp2f(-9.96578428466209f * (float)idx * (1.f / 512.f));
        }
    } else if (bid < 257) {               // out = features + fc2_b
        const float4v* f4 = (const float4v*)features;
        float4v* o4 = (float4v*)out;
        const float4v* b4 = (const float4v*)fc2_b;
        long base = (long)(bid - 1) * 1024;
        #pragma unroll
        for (int i = 0; i < 4; ++i) {
            long idx = base + tid + i * 256;
            o4[idx] = f4[idx] + b4[idx & 15];
        }
    } else if (bid < 1281) {              // wdT = (wq - wk)^T
        int tt = bid - 257;  conv_t_dev(wq, wk, wdT, 1024, 1024, tt & 31, tt >> 5, tid, t);
    } else if (bid < 2305) {              // wvT
        int tt = bid - 1281; conv_t_dev(wv, nullptr, wvT, 1024, 1024, tt & 31, tt >> 5, tid, t);
    } else if (bid < 3329) {              // g1T
        int tt = bid - 2305; conv_t_dev(g1_w, nullptr, g1T, 1024, 1024, tt & 31, tt >> 5, tid, t);
    } else if (bid < 4353) {              // g2T
        int tt = bid - 3329; conv_t_dev(g2_w, nullptr, g2T, 1024, 1024, tt & 31, tt >> 5, tid, t);
    } else if (bid < 4417) {              // fc2T (K=1024, N=64)
        int tt = bid - 4353; conv_t_dev(fc2_w, nullptr, fc2T, 1024, 64, tt & 1, tt >> 1, tid, t);
    } else if (bid < 4433) {              // wd2T
        int tt = bid - 4417; conv_t_dev(wq2, wk2, wd2T, 128, 128, tt & 3, tt >> 2, tid, t);
    } else if (bid < 4449) {              // gg1T
        int tt = bid - 4433; conv_t_dev(gg1_w, nullptr, gg1T, 128, 128, tt & 3, tt >> 2, tid, t);
    } else if (bid < 4465) {              // gg2T
        int tt = bid - 4449; conv_t_dev(gg2_w, nullptr, gg2T, 128, 128, tt & 3, tt >> 2, tid, t);
    } else {                              // x-GEMM tiles (1024)
        xgemm_dev(features, fc1_w, fc1_b, xb, bid - 4465, tid, smem);
    }
}

// ------------- 64x128 GEMM, BK=32, counted-vmcnt double-buffer --------------
template <int OP, bool CS>
static __device__ void gemm64_dev(
    const __hip_bfloat16* __restrict__ A, const __hip_bfloat16* __restrict__ Bt,
    const float* __restrict__ bias, __hip_bfloat16* __restrict__ Co,
    float scale, float* __restrict__ pcs, int swz, int tid, char* smem)
{
    const int wid = tid >> 6, lane = tid & 63;
    const int bm = (swz >> 3) << 6, bn = (swz & 7) << 7;
    const int wm = (wid >> 1) << 5, wn = (wid & 1) << 6;
    f32x4 acc[2][4] = {};
    const int rA = tid >> 2, c0 = (tid & 3) << 3;
    const int rB1 = (tid + 256) >> 2;
    const int l15 = lane & 15, kg = lane >> 4;
    const int arow = wm + l15, brow = wn + l15;

#define G64_STAGE(b, k0)                                                        \
    { char* base = smem + (b) * 12288;                                          \
      GLOAD_LDS16(A + (long)(bm + rA) * 1024 + (k0) + c0, base + (wid << 6) * 16); \
      GLOAD_LDS16(Bt + (long)(bn + rA) * 1024 + (k0) + c0,                      \
                  base + 4096 + (wid << 6) * 16);                               \
      GLOAD_LDS16(Bt + (long)(bn + rB1) * 1024 + (k0) + c0,                     \
                  base + 4096 + (256 + (wid << 6)) * 16); }

    G64_STAGE(0, 0);
    #pragma unroll 2
    for (int kt = 0; kt < 32; ++kt) {
        if (kt < 31) {
            G64_STAGE((kt + 1) & 1, (kt + 1) * 32);
            asm volatile("s_waitcnt vmcnt(3)" ::: "memory");
        } else {
            asm volatile("s_waitcnt vmcnt(0)" ::: "memory");
        }
        __builtin_amdgcn_s_barrier();
        __builtin_amdgcn_sched_barrier(0);
        const __hip_bfloat16* As = (const __hip_bfloat16*)(smem + (kt & 1) * 12288);
        const __hip_bfloat16* Bs = (const __hip_bfloat16*)(smem + (kt & 1) * 12288 + 4096);
        short8 af[2], bf_[4];
        #pragma unroll
        for (int m = 0; m < 2; ++m)
            af[m] = ((const short8*)As)[(arow + m * 16) * 4 + kg];
        #pragma unroll
        for (int n = 0; n < 4; ++n)
            bf_[n] = ((const short8*)Bs)[(brow + n * 16) * 4 + kg];
        __builtin_amdgcn_s_setprio(1);
        #pragma unroll
        for (int m = 0; m < 2; ++m)
            #pragma unroll
            for (int n = 0; n < 4; ++n)
                acc[m][n] = __builtin_amdgcn_mfma_f32_16x16x32_bf16(
                    af[m], bf_[n], acc[m][n], 0, 0, 0);
        __builtin_amdgcn_s_setprio(0);
        __builtin_amdgcn_s_barrier();
    }
#undef G64_STAGE

    const int rq = kg << 2;
    float csum[4];
    #pragma unroll
    for (int n = 0; n < 4; ++n) {
        const int col = bn + wn + n * 16 + l15;
        const float bv = bias ? bias[col] : 0.f;
        csum[n] = 0.f;
        #pragma unroll
        for (int m = 0; m < 2; ++m) {
            #pragma unroll
            for (int j = 0; j < 4; ++j) {
                const int row = bm + wm + m * 16 + rq + j;
                float cv = acc[m][n][j] + bv;
                if (OP == 1) cv = fmaxf(cv, 0.f);
                if (OP == 2) cv = __expf(cv * scale);
                if (CS) csum[n] += cv;
                Co[(long)row * 1024 + col] = __float2bfloat16(cv);
            }
        }
    }
    if (CS) {
        __syncthreads();
        float* ps = (float*)smem;  // [128 col_local][8 slot]
        const int slot = ((wid >> 1) << 2) | kg;
        #pragma unroll
        for (int n = 0; n < 4; ++n)
            ps[(wn + n * 16 + l15) * 8 + slot] = csum[n];
        __syncthreads();
        if (tid < 128) {
            float s = 0.f;
            #pragma unroll
            for (int q = 0; q < 8; ++q) s += ps[tid * 8 + q];
            pcs[(long)(swz >> 3) * 1024 + bn + tid] = s;
        }
    }
}

template <int OP, bool CS>
__global__ __launch_bounds__(256) void gemm64_k(
    const __hip_bfloat16* __restrict__ A, const __hip_bfloat16* __restrict__ Bt,
    const float* __restrict__ bias, __hip_bfloat16* __restrict__ Co,
    float scale, float* __restrict__ pcs)
{
    __shared__ __align__(16) char smem[24576];
    const int swz = xcd_swz(blockIdx.y * gridDim.x + blockIdx.x, gridDim.x * gridDim.y);
    gemm64_dev<OP, CS>(A, Bt, bias, Co, scale, pcs, swz, threadIdx.x, smem);
}

// ---------------- fused group-MLP chain (device fn) ----------------
static __device__ void chain_dev(
    const __hip_bfloat16* __restrict__ xb,
    const __hip_bfloat16* __restrict__ w1T,
    const __hip_bfloat16* __restrict__ w2T,
    const __hip_bfloat16* __restrict__ w3T,
    const float* __restrict__ b2, const float* __restrict__ b3,
    __hip_bfloat16* __restrict__ e1, float* __restrict__ pcs1,
    int tileIdx, int tid, char* smem)
{
    unsigned short* act = (unsigned short*)smem;            // 32 KB swizzled
    unsigned short* Wb  = (unsigned short*)(smem + 32768);  // 32 KB swizzled
    const int wid = tid >> 6, lane = tid & 63;
    const int wm = (wid >> 1) << 6, wn = (wid & 1) << 6;
    const long tile = (long)tileIdx * (128 * 128);

    #pragma unroll
    for (int i = 0; i < 8; ++i) {
        int L = i * 256 + wid * 64 + lane;
        int r = L >> 4, c16o = (L & 15) ^ (r & 7);
        GLOAD_LDS16(xb + tile + r * 128 + c16o * 8,
                    (char*)act + (i * 256 + wid * 64) * 16);
        GLOAD_LDS16(w1T + r * 128 + c16o * 8,
                    (char*)Wb + (i * 256 + wid * 64) * 16);
    }
    __syncthreads();

    f32x4 acc[4][4];
    const int rq = (lane >> 4) << 2;

#define CHAIN_ZERO()                                                            \
    _Pragma("unroll") for (int m = 0; m < 4; ++m)                               \
        _Pragma("unroll") for (int n = 0; n < 4; ++n)                           \
            acc[m][n] = (f32x4){0.f, 0.f, 0.f, 0.f};

#define CHAIN_MM()                                                              \
    _Pragma("unroll") for (int ks = 0; ks < 4; ++ks) {                          \
        short8 af[4], bfv[4];                                                   \
        const int kc = ks * 4 + (lane >> 4);                                    \
        _Pragma("unroll") for (int m = 0; m < 4; ++m) {                         \
            int r = wm + m * 16 + (lane & 15);                                  \
            af[m] = *(const short8*)((const char*)act + swz16(r, kc) * 16);     \
        }                                                                       \
        _Pragma("unroll") for (int n = 0; n < 4; ++n) {                         \
            int r = wn + n * 16 + (lane & 15);                                  \
            bfv[n] = *(const short8*)((const char*)Wb + swz16(r, kc) * 16);     \
        }                                                                       \
        _Pragma("unroll") for (int m = 0; m < 4; ++m)                           \
            _Pragma("unroll") for (int n = 0; n < 4; ++n)                       \
                acc[m][n] = __builtin_amdgcn_mfma_f32_16x16x32_bf16(            \
                    af[m], bfv[n], acc[m][n], 0, 0, 0);                         \
    }

#define STAGE_W(wptr)                                                           \
    _Pragma("unroll") for (int i = 0; i < 8; ++i) {                             \
        int L = i * 256 + wid * 64 + lane;                                      \
        int r = L >> 4, c16o = (L & 15) ^ (r & 7);                              \
        GLOAD_LDS16((wptr) + r * 128 + c16o * 8,                                \
                    (char*)Wb + (i * 256 + wid * 64) * 16);                     \
    }

    CHAIN_ZERO(); CHAIN_MM();
    __syncthreads();
    STAGE_W(w2T);
    #pragma unroll
    for (int m = 0; m < 4; ++m)
        #pragma unroll
        for (int n = 0; n < 4; ++n)
            #pragma unroll
            for (int j = 0; j < 4; ++j) {
                int row = wm + m * 16 + rq + j, col = wn + n * 16 + (lane & 15);
                act[swz_elem(row, col)] = f2bf_bits(acc[m][n][j]);
            }
    __syncthreads();

    CHAIN_ZERO(); CHAIN_MM();
    __syncthreads();
    STAGE_W(w3T);
    {
        float bv[4];
        #pragma unroll
        for (int n = 0; n < 4; ++n) bv[n] = b2[wn + n * 16 + (lane & 15)];
        #pragma unroll
        for (int m = 0; m < 4; ++m)
            #pragma unroll
            for (int n = 0; n < 4; ++n)
                #pragma unroll
                for (int j = 0; j < 4; ++j) {
                    int row = wm + m * 16 + rq + j, col = wn + n * 16 + (lane & 15);
                    act[swz_elem(row, col)] = f2bf_bits(fmaxf(acc[m][n][j] + bv[n], 0.f));
                }
    }
    __syncthreads();

    CHAIN_ZERO(); CHAIN_MM();
    __syncthreads();
    {
        float bv[4];
        #pragma unroll
        for (int n = 0; n < 4; ++n) bv[n] = b3[wn + n * 16 + (lane & 15)];
        #pragma unroll
        for (int m = 0; m < 4; ++m)
            #pragma unroll
            for (int n = 0; n < 4; ++n)
                #pragma unroll
                for (int j = 0; j < 4; ++j) {
                    int row = wm + m * 16 + rq + j, col = wn + n * 16 + (lane & 15);
                    float ev = __expf((acc[m][n][j] + bv[n]) * 0.08838834764831845f);
                    act[swz_elem(row, col)] = f2bf_bits(ev);
                }
    }
    __syncthreads();

    #pragma unroll
    for (int i = 0; i < 8; ++i) {
        int idx = i * 256 + tid;
        int r = idx >> 4, c16o = idx & 15;
        short8 vd = *(const short8*)((const char*)act + swz16(r, c16o) * 16);
        *(short8*)((__hip_bfloat16*)e1 + tile + r * 128 + c16o * 8) = vd;
    }
    #pragma unroll
    for (int i = 0; i < 4; ++i) {
        int p = i * 256 + tid;
        int g = p >> 7, c = p & 127;
        float s = 0.f;
        #pragma unroll
        for (int t16 = 0; t16 < 16; ++t16) {
            int r = t16 * 8 + g;
            s += bf_bits2f(act[swz_elem(r, c)]);
        }
        pcs1[(long)tileIdx * 1024 + p] = s;
    }
#undef CHAIN_ZERO
#undef CHAIN_MM
#undef STAGE_W
}

// mid: blocks 0..255 = tail GEMM 1 (d2 = gf2 @ wd), 256..1279 = chain tiles
__global__ __launch_bounds__(256) void mid_k(
    const __hip_bfloat16* __restrict__ xb, const __hip_bfloat16* __restrict__ wdT,
    __hip_bfloat16* __restrict__ d2b,
    const __hip_bfloat16* __restrict__ wd2T, const __hip_bfloat16* __restrict__ gg1T,
    const __hip_bfloat16* __restrict__ gg2T, const float* __restrict__ gg1_b,
    const float* __restrict__ gg2_b, __hip_bfloat16* __restrict__ e1,
    float* __restrict__ pcs1)
{
    __shared__ __align__(16) char smem[65536];
    const int bid = blockIdx.x, tid = threadIdx.x;
    if (bid < 256) {
        gemm64_dev<0, false>(xb + (size_t)14336 * 1024, wdT, nullptr, d2b,
                             0.f, nullptr, xcd_swz(bid, 256), tid, smem);
    } else {
        chain_dev(xb, wd2T, gg1T, gg2T, gg1_b, gg2_b, e1, pcs1, bid - 256, tid, smem);
    }
}

// reduce: blocks 0-15 -> rcs1, 16-31 -> rcs2
__global__ __launch_bounds__(1024) void reduce_k(
    const float* __restrict__ pcs1, const float* __restrict__ pcs2,
    float* __restrict__ rcs1, float* __restrict__ rcs2)
{
    __shared__ float red[16][64];
    const int tx = threadIdx.x, ty = threadIdx.y;
    if (blockIdx.x < 16) {
        const int col = blockIdx.x * 64 + tx;
        float s = 0.f;
        for (int p = ty; p < 1024; p += 16) s += pcs1[(long)p * 1024 + col];
        red[ty][tx] = s;
        __syncthreads();
        if (ty == 0) {
            float t = 0.f;
            #pragma unroll
            for (int q = 0; q < 16; ++q) t += red[q][tx];
            rcs1[col] = 1.f / t;
        }
    } else {
        const int col = (blockIdx.x - 16) * 64 + tx;
        float s = 0.f;
        for (int p = ty; p < 32; p += 16) s += pcs2[(long)p * 1024 + col];
        red[ty][tx] = s;
        __syncthreads();
        if (ty == 0) {
            float t = 0.f;
            #pragma unroll
            for (int q = 0; q < 16; ++q) t += red[q][tx];
            rcs2[col] = 1.f / t;
        }
    }
}

// ---- v-GEMM (BK=64 dbuf, counted vmcnt) + res epilogue + out-accum ----
__global__ __launch_bounds__(256) void gemm_v_res_out(
    const __hip_bfloat16* __restrict__ A, const __hip_bfloat16* __restrict__ Bt,
    const __hip_bfloat16* __restrict__ e1, const __hip_bfloat16* __restrict__ e2,
    const float* __restrict__ rcs1, const float* __restrict__ rcs2,
    const float* __restrict__ invde, const float* __restrict__ feats,
    const float* __restrict__ lpe, const __hip_bfloat16* __restrict__ fc2T,
    float* __restrict__ out)
{
    __shared__ __align__(16) char smem[65536];            // 2x(As 16K + Bs 16K)
    unsigned short* st = (unsigned short*)smem;           // [128][136] epilogue union

    const int tid = threadIdx.x;
    const int wid = tid >> 6;
    const int lane = tid & 63;
    const int swz = xcd_swz(blockIdx.y * gridDim.x + blockIdx.x, gridDim.x * gridDim.y);
    const int bm = (swz >> 3) << 7, bn = (swz & 7) << 7;
    const int wm = (wid >> 1) << 6, wn = (wid & 1) << 6;

    f32x4 acc[4][4] = {};
    const int c8 = tid & 7;
    const int l15 = lane & 15;
    const int kg = lane >> 4;
    const int arow = wm + l15;
    const int brow = wn + l15;

#define VR_STAGE(b, k0)                                                         \
    { char* base = smem + (b) * 32768;                                          \
      _Pragma("unroll") for (int i = 0; i < 4; ++i) {                           \
        const int r = i * 32 + (tid >> 3);                                      \
        const int c8s = c8 ^ (r & 7);                                           \
        GLOAD_LDS16(A + (long)(bm + r) * 1024 + (k0) + c8s * 8,                 \
                    base + (i * 256 + wid * 64) * 16);                          \
        GLOAD_LDS16(Bt + (long)(bn + r) * 1024 + (k0) + c8s * 8,                \
                    base + 16384 + (i * 256 + wid * 64) * 16); } }

    VR_STAGE(0, 0);
    #pragma unroll 2
    for (int kt = 0; kt < 16; ++kt) {
        if (kt < 15) {
            VR_STAGE((kt + 1) & 1, (kt + 1) * 64);
            asm volatile("s_waitcnt vmcnt(8)" ::: "memory");
        } else {
            asm volatile("s_waitcnt vmcnt(0)" ::: "memory");
        }
        __builtin_amdgcn_s_barrier();
        __builtin_amdgcn_sched_barrier(0);
        const __hip_bfloat16* As = (const __hip_bfloat16*)(smem + (kt & 1) * 32768);
        const __hip_bfloat16* Bs = (const __hip_bfloat16*)(smem + (kt & 1) * 32768 + 16384);
        __builtin_amdgcn_s_setprio(1);
        #pragma unroll
        for (int ks2 = 0; ks2 < 2; ++ks2) {
            const int kslot = ks2 * 4 + kg;
            short8 af[4], bf_[4];
            #pragma unroll
            for (int m = 0; m < 4; ++m) {
                const int r = arow + m * 16;
                af[m] = *(const short8*)(As + (r * 8 + (kslot ^ (r & 7))) * 8);
            }
            #pragma unroll
            for (int n = 0; n < 4; ++n) {
                const int r = brow + n * 16;
                bf_[n] = *(const short8*)(Bs + (r * 8 + (kslot ^ (r & 7))) * 8);
            }
            #pragma unroll
            for (int m = 0; m < 4; ++m)
                #pragma unroll
                for (int n = 0; n < 4; ++n)
                    acc[m][n] = __builtin_amdgcn_mfma_f32_16x16x32_bf16(
                        af[m], bf_[n], acc[m][n], 0, 0, 0);
        }
        __builtin_amdgcn_s_setprio(0);
        __builtin_amdgcn_s_barrier();
    }
#undef VR_STAGE

    // v tile -> st (bf16)
    const int rq = kg << 2;
    #pragma unroll
    for (int m = 0; m < 4; ++m)
        #pragma unroll
        for (int n = 0; n < 4; ++n)
            #pragma unroll
            for (int j = 0; j < 4; ++j)
                st[(wm + m * 16 + rq + j) * 136 + wn + n * 16 + l15] =
                    f2bf_bits(acc[m][n][j]);
    __syncthreads();

    // res = (e1*rcs1 + e2*rcs2) * (v + pe) -> st in place (vectorized)
    const float lp = lpe[0];
    #pragma unroll
    for (int p = 0; p < 4; ++p) {
        const int r = p * 32 + (tid >> 3);
        const int cc = (tid & 7) << 4;
        const int grow = bm + r;
        const float angs = 100.f * feats[(long)grow * 64];
        const long goff = (long)grow * 1024 + bn + cc;
        const long goff2 = (long)(grow & 2047) * 1024 + bn + cc;
        short8 ev1[2], ev2[2], sv[2];
        ev1[0] = *(const short8*)((const unsigned short*)e1 + goff);
        ev1[1] = *(const short8*)((const unsigned short*)e1 + goff + 8);
        ev2[0] = *(const short8*)((const unsigned short*)e2 + goff2);
        ev2[1] = *(const short8*)((const unsigned short*)e2 + goff2 + 8);
        sv[0] = *(const short8*)&st[r * 136 + cc];
        sv[1] = *(const short8*)&st[r * 136 + cc + 8];
        unsigned short ov[16];
        #pragma unroll
        for (int q = 0; q < 16; ++q) {
            const int h = bn + cc + q;
            const float ang = angs * invde[h & 511];
            const float tr = (h < 512) ? __sinf(ang) : __cosf(ang);
            const float a = bf_bits2f((unsigned short)ev1[q >> 3][q & 7]) * rcs1[h] +
                            bf_bits2f((unsigned short)ev2[q >> 3][q & 7]) * rcs2[h];
            const float vv = bf_bits2f((unsigned short)sv[q >> 3][q & 7]);
            ov[q] = f2bf_bits(a * (vv + (tr + lp) * lp));
        }
        *(short8*)&st[r * 136 + cc] = *(short8*)&ov[0];
        *(short8*)&st[r * 136 + cc + 8] = *(short8*)&ov[8];
    }
    __syncthreads();

    // out[bm:+128, :] += res_tile @ fc2_w[bn:+128, :]
    {
        const int wmO = wid << 5;
        f32x4 aco[2][4] = {};
        #pragma unroll
        for (int ks = 0; ks < 4; ++ks) {
            short8 afo[2], bfo[4];
            #pragma unroll
            for (int m = 0; m < 2; ++m)
                afo[m] = *(const short8*)&st[(wmO + m * 16 + l15) * 136 + ks * 32 + kg * 8];
            #pragma unroll
            for (int n = 0; n < 4; ++n)
                bfo[n] = *(const short8*)((const unsigned short*)fc2T +
                                          (long)(n * 16 + l15) * 1024 + bn + ks * 32 + kg * 8);
            #pragma unroll
            for (int m = 0; m < 2; ++m)
                #pragma unroll
                for (int n = 0; n < 4; ++n)
                    aco[m][n] = __builtin_amdgcn_mfma_f32_16x16x32_bf16(
                        afo[m], bfo[n], aco[m][n], 0, 0, 0);
        }
        #pragma unroll
        for (int m = 0; m < 2; ++m)
            #pragma unroll
            for (int n = 0; n < 4; ++n)
                #pragma unroll
                for (int j = 0; j < 4; ++j) {
                    const int row = bm + wmO + m * 16 + rq + j;
                    atomicAdd(&out[(long)row * 64 + n * 16 + l15], aco[m][n][j]);
                }
    }
}

extern "C" void kernel_launch(void* const* d_in, const int* in_sizes, int n_in,
                              void* d_out, int out_size, void* d_ws, size_t ws_size,
                              hipStream_t stream) {
    const float* features = (const float*)d_in[0];
    const float* fc1_w = (const float*)d_in[1];
    const float* fc1_b = (const float*)d_in[2];
    const float* fc2_w = (const float*)d_in[3];
    const float* fc2_b = (const float*)d_in[4];
    const float* g1_w = (const float*)d_in[5];
    const float* g1_b = (const float*)d_in[6];
    const float* g2_w = (const float*)d_in[7];
    const float* g2_b = (const float*)d_in[8];
    const float* gg1_w = (const float*)d_in[9];
    const float* gg1_b = (const float*)d_in[10];
    const float* gg2_w = (const float*)d_in[11];
    const float* gg2_b = (const float*)d_in[12];
    const float* wq = (const float*)d_in[13];
    const float* wk = (const float*)d_in[14];
    const float* wv = (const float*)d_in[15];
    const float* wq2 = (const float*)d_in[16];
    const float* wk2 = (const float*)d_in[17];
    const float* lpe = (const float*)d_in[18];
    float* out = (float*)d_out;

    char* ws = (char*)d_ws;
    const size_t MB = 1024ull * 1024ull;
    __hip_bfloat16* xb   = (__hip_bfloat16*)ws;                 // 32 MB
    __hip_bfloat16* e1   = (__hip_bfloat16*)(ws + 32 * MB);     // 32 MB
    __hip_bfloat16* d2b  = (__hip_bfloat16*)(ws + 64 * MB);     // 4 MB
    __hip_bfloat16* t2b  = (__hip_bfloat16*)(ws + 68 * MB);     // 4 MB
    __hip_bfloat16* e2b  = (__hip_bfloat16*)(ws + 72 * MB);     // 4 MB
    float*          pcs1 = (float*)(ws + 76 * MB);              // 4 MB
    float*          pcs2 = (float*)(ws + 80 * MB);              // 128 KB
    char* W = ws + 81 * MB;
    __hip_bfloat16* wdT   = (__hip_bfloat16*)W;                 // 2 MB
    __hip_bfloat16* wvT   = (__hip_bfloat16*)(W + 2 * MB);      // 2 MB
    __hip_bfloat16* g1T   = (__hip_bfloat16*)(W + 4 * MB);      // 2 MB
    __hip_bfloat16* g2T   = (__hip_bfloat16*)(W + 6 * MB);      // 2 MB
    __hip_bfloat16* fc2T  = (__hip_bfloat16*)(W + 8 * MB);      // 128 KB
    __hip_bfloat16* wd2T  = (__hip_bfloat16*)(W + 8 * MB + 256 * 1024);
    __hip_bfloat16* gg1T  = (__hip_bfloat16*)(W + 8 * MB + 320 * 1024);
    __hip_bfloat16* gg2T  = (__hip_bfloat16*)(W + 8 * MB + 384 * 1024);
    float* rcs1  = (float*)(W + 9 * MB);                        // 4 KB
    float* rcs2  = rcs1 + 1024;
    float* invde = rcs2 + 1024;                                 // 512

    // 1. prep (transposes, out-init, invde) + x-GEMM from fp32
    prep_x_k<<<5489, 256, 0, stream>>>(
        features, fc1_w, fc1_b, fc2_w, fc2_b, g1_w, g2_w, wq, wk, wv, wq2, wk2,
        gg1_w, gg2_w, fc2T, wdT, wvT, g1T, g2T, wd2T, gg1T, gg2T, xb, invde, out);

    // 2. chain (1024 tiles) + tail GEMM 1 (256 tiles) in one launch
    mid_k<<<1280, 256, 0, stream>>>(xb, wdT, d2b, wd2T, gg1T, gg2T,
                                    gg1_b, gg2_b, e1, pcs1);

    // 3-4. tail GEMMs 2,3 (dbuf, counted vmcnt)
    gemm64_k<1, false><<<dim3(8, 32), 256, 0, stream>>>(d2b, g1T, g1_b, t2b, 0.f, nullptr);
    gemm64_k<2, true><<<dim3(8, 32), 256, 0, stream>>>(t2b, g2T, g2_b, e2b, 0.03125f, pcs2);

    // 5. softmax denominators -> reciprocals
    reduce_k<<<32, dim3(64, 16), 0, stream>>>(pcs1, pcs2, rcs1, rcs2);

    // 6. v-GEMM + res epilogue + out-accum
    gemm_v_res_out<<<dim3(8, 128), 256, 0, stream>>>(
        xb, wvT, e1, e2b, rcs1, rcs2, invde, features, lpe, fc2T, out);
}